// Round 10
// baseline (275.752 us; speedup 1.0000x reference)
//
#include <hip/hip_runtime.h>

#define N_NODES 50000
#define E_EDGES 800000
#define SCAN_NBLK 196   // ceil(50000/256)

__device__ __forceinline__ unsigned short f2bf(float f) {
    unsigned u = __float_as_uint(f);
    u = (u + 0x7FFF + ((u >> 16) & 1)) >> 16;   // RNE
    return (unsigned short)u;
}
__device__ __forceinline__ float bf2f(unsigned short s) {
    return __uint_as_float(((unsigned)s) << 16);
}

// ---------------- CSR build ----------------

__global__ void k_count(const int* __restrict__ dst, int* __restrict__ cnt) {
    int e = blockIdx.x * blockDim.x + threadIdx.x;
    if (e < E_EDGES) atomicAdd(&cnt[dst[e]], 1);
}

__global__ void k_scan_part(const int* __restrict__ cnt, int* __restrict__ excl,
                            int* __restrict__ bsum) {
    __shared__ int sm[256];
    int b = blockIdx.x, t = threadIdx.x;
    int i = b * 256 + t;
    int v = (i < N_NODES) ? cnt[i] : 0;
    sm[t] = v;
    __syncthreads();
    for (int off = 1; off < 256; off <<= 1) {
        int u = (t >= off) ? sm[t - off] : 0;
        __syncthreads();
        sm[t] += u;
        __syncthreads();
    }
    if (i < N_NODES) excl[i] = sm[t] - v;
    if (t == 255) bsum[b] = sm[255];
}

__global__ void k_scan_bsum(const int* __restrict__ bsum, int* __restrict__ boff) {
    __shared__ int sm[256];
    int t = threadIdx.x;
    int v = (t < SCAN_NBLK) ? bsum[t] : 0;
    sm[t] = v;
    __syncthreads();
    for (int off = 1; off < 256; off <<= 1) {
        int u = (t >= off) ? sm[t - off] : 0;
        __syncthreads();
        sm[t] += u;
        __syncthreads();
    }
    if (t < SCAN_NBLK) boff[t] = sm[t] - v;
}

__global__ void k_scan_add(int* __restrict__ rowptr, const int* __restrict__ boff,
                           int* __restrict__ cursor) {
    int b = blockIdx.x, t = threadIdx.x;
    int i = b * 256 + t;
    if (i < N_NODES) {
        int r = rowptr[i] + boff[b];
        rowptr[i] = r;
        cursor[i] = r;
    }
    if (i == 0) rowptr[N_NODES] = E_EDGES;
}

__global__ void k_fill(const int* __restrict__ src, const int* __restrict__ dst,
                       int* __restrict__ cursor, int* __restrict__ eidx) {
    int e = blockIdx.x * blockDim.x + threadIdx.x;
    if (e < E_EDGES) {
        int p = atomicAdd(&cursor[dst[e]], 1);
        eidx[p] = src[e];
    }
}

// ---------------- weights / cast ----------------

// WT[k*ldd + col_off + o] = W[o*K + k]
__global__ void k_transpose(const float* __restrict__ W, float* __restrict__ WT,
                            int O, int K, int ldd, int col_off) {
    int idx = blockIdx.x * blockDim.x + threadIdx.x;
    if (idx < O * K) {
        int o = idx / K, k = idx - o * K;
        WT[k * ldd + col_off + o] = W[idx];
    }
}

// xb = bf16(x), vectorized
__global__ void k_cast(const float* __restrict__ x, unsigned short* __restrict__ xb) {
    int tid = blockIdx.x * blockDim.x + threadIdx.x;
    const int total4 = N_NODES * 32;       // float4 groups
    for (int i = tid; i < total4; i += gridDim.x * blockDim.x) {
        float4 v = ((const float4*)x)[i];
        ushort4 o;
        o.x = f2bf(v.x); o.y = f2bf(v.y); o.z = f2bf(v.z); o.w = f2bf(v.w);
        ((ushort4*)xb)[i] = o;
    }
}

// ---------------- gathers ----------------

// mean[i,:] = (1/max(deg,1)) * sum_j xb[j,:]  (bf16 reads, fp32 accumulate)
// block 256 thr = 8 nodes x 32 lanes; lane owns 4 features (ushort4 = 8B/edge/lane).
__global__ void k_gather128(const int* __restrict__ rowptr, const int* __restrict__ eidx,
                            const unsigned short* __restrict__ xb,
                            float* __restrict__ mean) {
    int t = threadIdx.x;
    int i = blockIdx.x * 8 + (t >> 5);
    int g = t & 31;
    if (i >= N_NODES) return;
    int beg = rowptr[i], end = rowptr[i + 1];
    float a0 = 0.f, a1 = 0.f, a2 = 0.f, a3 = 0.f;
    int j = beg;
    for (; j + 3 < end; j += 4) {
        int s0 = eidx[j], s1 = eidx[j + 1], s2 = eidx[j + 2], s3 = eidx[j + 3];
        ushort4 u0 = *(const ushort4*)&xb[(size_t)s0 * 128 + g * 4];
        ushort4 u1 = *(const ushort4*)&xb[(size_t)s1 * 128 + g * 4];
        ushort4 u2 = *(const ushort4*)&xb[(size_t)s2 * 128 + g * 4];
        ushort4 u3 = *(const ushort4*)&xb[(size_t)s3 * 128 + g * 4];
        a0 += bf2f(u0.x) + bf2f(u1.x) + bf2f(u2.x) + bf2f(u3.x);
        a1 += bf2f(u0.y) + bf2f(u1.y) + bf2f(u2.y) + bf2f(u3.y);
        a2 += bf2f(u0.z) + bf2f(u1.z) + bf2f(u2.z) + bf2f(u3.z);
        a3 += bf2f(u0.w) + bf2f(u1.w) + bf2f(u2.w) + bf2f(u3.w);
    }
    for (; j < end; ++j) {
        ushort4 u = *(const ushort4*)&xb[(size_t)eidx[j] * 128 + g * 4];
        a0 += bf2f(u.x); a1 += bf2f(u.y); a2 += bf2f(u.z); a3 += bf2f(u.w);
    }
    float inv = 1.0f / fmaxf((float)(end - beg), 1.0f);
    float4 r; r.x = a0 * inv; r.y = a1 * inv; r.z = a2 * inv; r.w = a3 * inv;
    *(float4*)&mean[(size_t)i * 128 + g * 4] = r;
}

// out[i,o] = z[i,80][40+o] + inv * sum_j z[j,80][o]  (o < 40)
// block 320 thr = 8 nodes x 40 lanes (grid*8 == N exactly)
__global__ void k_gather40(const int* __restrict__ rowptr, const int* __restrict__ eidx,
                           const float* __restrict__ z, float* __restrict__ out) {
    int t = threadIdx.x;
    int i = blockIdx.x * 8 + t / 40;
    int o = t % 40;
    int beg = rowptr[i], end = rowptr[i + 1];
    float acc = 0.0f;
    int j = beg;
    for (; j + 3 < end; j += 4) {
        int s0 = eidx[j], s1 = eidx[j + 1], s2 = eidx[j + 2], s3 = eidx[j + 3];
        acc += z[(size_t)s0 * 80 + o] + z[(size_t)s1 * 80 + o]
             + z[(size_t)s2 * 80 + o] + z[(size_t)s3 * 80 + o];
    }
    for (; j < end; ++j)
        acc += z[(size_t)eidx[j] * 80 + o];
    float inv = 1.0f / fmaxf((float)(end - beg), 1.0f);
    out[(size_t)i * 40 + o] = z[(size_t)i * 80 + 40 + o] + acc * inv;
}

// ---------------- layer 1 dense (LDS-B, J=4) ----------------
// h[M,128] = relu([mean|x][M,256] @ B1cat[256,128] + b1)
// BM=128, BN=64 (cblk halves) -> grid 782. 256 thr: og=t&7 -> cols {og*4..+3, 32+og*4..+3}
// (distinct banks, broadcast within og group = conflict-free), mg=t>>3 -> 4 nodes.
// Per kk: 32B LDS / 32 FMA = 1 B/FMA -> ~30 us LDS floor, FMA floor 21 us.
__launch_bounds__(256)
__global__ void k_dense1(const float* __restrict__ mean, const float* __restrict__ x,
                         const float* __restrict__ Bcat,  // [256][128]
                         const float* __restrict__ b1, float* __restrict__ h) {
    __shared__ float Bs[64][64];
    int t = threadIdx.x;
    int og = t & 7, mg = t >> 3;
    int og4 = og * 4;
    int nblk = blockIdx.x >> 1, cblk = blockIdx.x & 1;
    int node0 = nblk * 128;
    int cb = cblk * 64;

    int mr[4];
#pragma unroll
    for (int j = 0; j < 4; ++j)
        mr[j] = min(node0 + mg * 4 + j, N_NODES - 1);

    float acc[4][8];
#pragma unroll
    for (int j = 0; j < 4; ++j)
#pragma unroll
        for (int q = 0; q < 8; ++q) acc[j][q] = 0.0f;

    for (int kt = 0; kt < 4; ++kt) {
        const float* __restrict__ Asrc = (kt < 2) ? mean : x;
        int kbase = (kt & 1) * 64;

        __syncthreads();
#pragma unroll
        for (int p = 0; p < 4; ++p) {
            int idx = t + p * 256;                // float4 idx in 64x64 tile
            int row = idx >> 4, q4 = (idx & 15) * 4;
            *(float4*)&Bs[row][q4] =
                *(const float4*)&Bcat[(size_t)(kt * 64 + row) * 128 + cb + q4];
        }
        __syncthreads();

#pragma unroll 2
        for (int k4 = 0; k4 < 16; ++k4) {
            float4 av[4];
#pragma unroll
            for (int j = 0; j < 4; ++j)
                av[j] = *(const float4*)(Asrc + (size_t)mr[j] * 128 + kbase + k4 * 4);

#pragma unroll
            for (int u = 0; u < 4; ++u) {
                int kk = k4 * 4 + u;
                float4 bq0 = *(const float4*)&Bs[kk][og4];
                float4 bq1 = *(const float4*)&Bs[kk][32 + og4];
#pragma unroll
                for (int j = 0; j < 4; ++j) {
                    float a = (u == 0) ? av[j].x : (u == 1) ? av[j].y
                              : (u == 2) ? av[j].z : av[j].w;
                    acc[j][0] = fmaf(a, bq0.x, acc[j][0]);
                    acc[j][1] = fmaf(a, bq0.y, acc[j][1]);
                    acc[j][2] = fmaf(a, bq0.z, acc[j][2]);
                    acc[j][3] = fmaf(a, bq0.w, acc[j][3]);
                    acc[j][4] = fmaf(a, bq1.x, acc[j][4]);
                    acc[j][5] = fmaf(a, bq1.y, acc[j][5]);
                    acc[j][6] = fmaf(a, bq1.z, acc[j][6]);
                    acc[j][7] = fmaf(a, bq1.w, acc[j][7]);
                }
            }
        }
    }

    float bias[8];
#pragma unroll
    for (int q = 0; q < 4; ++q) bias[q] = b1[cb + og4 + q];
#pragma unroll
    for (int q = 0; q < 4; ++q) bias[4 + q] = b1[cb + 32 + og4 + q];

#pragma unroll
    for (int j = 0; j < 4; ++j) {
        int m = node0 + mg * 4 + j;
        if (m < N_NODES) {
            float4 r0, r1;
            r0.x = fmaxf(acc[j][0] + bias[0], 0.0f);
            r0.y = fmaxf(acc[j][1] + bias[1], 0.0f);
            r0.z = fmaxf(acc[j][2] + bias[2], 0.0f);
            r0.w = fmaxf(acc[j][3] + bias[3], 0.0f);
            r1.x = fmaxf(acc[j][4] + bias[4], 0.0f);
            r1.y = fmaxf(acc[j][5] + bias[5], 0.0f);
            r1.z = fmaxf(acc[j][6] + bias[6], 0.0f);
            r1.w = fmaxf(acc[j][7] + bias[7], 0.0f);
            *(float4*)&h[(size_t)m * 128 + cb + og4] = r0;
            *(float4*)&h[(size_t)m * 128 + cb + 32 + og4] = r1;
        }
    }
}

// ---------------- layer 2 dense (LDS-B, J=2) ----------------
// z[M,80] = h[M,128] @ B2cat[128,80] (+b2 on right half)
// BM=128, BN=40 (cblk halves) -> grid 782. og=t&3 (10 cols), mg=t>>2 (2 nodes).
__launch_bounds__(256)
__global__ void k_dense2(const float* __restrict__ h,
                         const float* __restrict__ Bcat,  // [128][80]
                         const float* __restrict__ b2, float* __restrict__ z) {
    __shared__ float Bs[128][40];
    int t = threadIdx.x;
    int og = t & 3, mg = t >> 2;
    int o0 = og * 10;
    int nblk = blockIdx.x >> 1, cblk = blockIdx.x & 1;
    int node0 = nblk * 128;
    int n0 = node0 + mg * 2;
    int mr0 = min(n0, N_NODES - 1);
    int mr1 = min(n0 + 1, N_NODES - 1);

#pragma unroll
    for (int p = 0; p < 5; ++p) {
        int idx = t + p * 256;                    // float4 idx in 128x40 tile
        int row = idx / 10, q4 = (idx - row * 10) * 4;
        *(float4*)&Bs[row][q4] =
            *(const float4*)&Bcat[(size_t)row * 80 + cblk * 40 + q4];
    }
    __syncthreads();

    float acc[2][10];
#pragma unroll
    for (int j = 0; j < 2; ++j)
#pragma unroll
        for (int q = 0; q < 10; ++q) acc[j][q] = 0.0f;

    const float* a0p = h + (size_t)mr0 * 128;
    const float* a1p = h + (size_t)mr1 * 128;

#pragma unroll 2
    for (int k4 = 0; k4 < 32; ++k4) {
        float4 av0 = *(const float4*)(a0p + k4 * 4);
        float4 av1 = *(const float4*)(a1p + k4 * 4);
#pragma unroll
        for (int u = 0; u < 4; ++u) {
            int kk = k4 * 4 + u;
            float bv[10];
#pragma unroll
            for (int q = 0; q < 5; ++q) {
                float2 b2v = *(const float2*)&Bs[kk][o0 + 2 * q];
                bv[2 * q] = b2v.x;
                bv[2 * q + 1] = b2v.y;
            }
            float e0 = (u == 0) ? av0.x : (u == 1) ? av0.y : (u == 2) ? av0.z : av0.w;
            float e1 = (u == 0) ? av1.x : (u == 1) ? av1.y : (u == 2) ? av1.z : av1.w;
#pragma unroll
            for (int q = 0; q < 10; ++q) {
                acc[0][q] = fmaf(e0, bv[q], acc[0][q]);
                acc[1][q] = fmaf(e1, bv[q], acc[1][q]);
            }
        }
    }

    float bias[10];
#pragma unroll
    for (int q = 0; q < 10; ++q)
        bias[q] = cblk ? b2[o0 + q] : 0.0f;

#pragma unroll
    for (int j = 0; j < 2; ++j) {
        int m = n0 + j;
        if (m < N_NODES) {
            size_t base = (size_t)m * 80 + cblk * 40 + o0;
#pragma unroll
            for (int q = 0; q < 5; ++q) {
                float2 r;
                r.x = acc[j][2 * q] + bias[2 * q];
                r.y = acc[j][2 * q + 1] + bias[2 * q + 1];
                *(float2*)&z[base + 2 * q] = r;
            }
        }
    }
}

// ---------------- launch ----------------

extern "C" void kernel_launch(void* const* d_in, const int* in_sizes, int n_in,
                              void* d_out, int out_size, void* d_ws, size_t ws_size,
                              hipStream_t stream) {
    const float* x   = (const float*)d_in[0];
    const int*   ei  = (const int*)d_in[1];      // [2, E] int32
    const float* W1l = (const float*)d_in[2];
    const float* b1  = (const float*)d_in[3];
    const float* W1r = (const float*)d_in[4];
    const float* W2l = (const float*)d_in[5];
    const float* b2  = (const float*)d_in[6];
    const float* W2r = (const float*)d_in[7];

    const int* src = ei;
    const int* dst = ei + E_EDGES;

    // ---- workspace carve (16B-aligned) ----
    char* base = (char*)d_ws;
    size_t off = 0;
    auto carve = [&](size_t bytes) {
        void* p = base + off;
        off += (bytes + 15) & ~(size_t)15;
        return p;
    };
    int*   cnt    = (int*)  carve((size_t)N_NODES * 4);
    int*   rowptr = (int*)  carve((size_t)(N_NODES + 1) * 4);
    int*   cursor = (int*)  carve((size_t)N_NODES * 4);
    int*   eidx   = (int*)  carve((size_t)E_EDGES * 4);
    int*   bsum   = (int*)  carve((size_t)256 * 4);
    int*   boff   = (int*)  carve((size_t)256 * 4);
    float* b1cat  = (float*)carve((size_t)256 * 128 * 4);            // [256][128]
    float* b2cat  = (float*)carve((size_t)128 * 80 * 4);             // [128][80]
    unsigned short* xb = (unsigned short*)carve((size_t)N_NODES * 128 * 2);
    float* mean   = (float*)carve((size_t)N_NODES * 128 * 4);
    float* h      = (float*)carve((size_t)N_NODES * 128 * 4);
    float* z      = mean;   // mean dead after k_dense1; z is N*80 < N*128
    float* outp   = (float*)d_out;

    // ---- CSR build ----
    hipMemsetAsync(cnt, 0, (size_t)N_NODES * 4, stream);
    k_count<<<(E_EDGES + 255) / 256, 256, 0, stream>>>(dst, cnt);
    k_scan_part<<<SCAN_NBLK, 256, 0, stream>>>(cnt, rowptr, bsum);
    k_scan_bsum<<<1, 256, 0, stream>>>(bsum, boff);
    k_scan_add<<<SCAN_NBLK, 256, 0, stream>>>(rowptr, boff, cursor);
    k_fill<<<(E_EDGES + 255) / 256, 256, 0, stream>>>(src, dst, cursor, eidx);

    // ---- weight prep + bf16 cast ----
    k_transpose<<<(16384 + 255) / 256, 256, 0, stream>>>(W1l, b1cat, 128, 128, 128, 0);
    k_transpose<<<(16384 + 255) / 256, 256, 0, stream>>>(W1r, b1cat + 128 * 128, 128, 128, 128, 0);
    k_transpose<<<(5120 + 255) / 256, 256, 0, stream>>>(W2l, b2cat, 40, 128, 80, 0);
    k_transpose<<<(5120 + 255) / 256, 256, 0, stream>>>(W2r, b2cat, 40, 128, 80, 40);
    k_cast<<<2048, 256, 0, stream>>>(x, xb);

    // ---- layer 1 ----
    k_gather128<<<(N_NODES + 7) / 8, 256, 0, stream>>>(rowptr, eidx, xb, mean);
    {
        int nblocks = ((N_NODES + 127) / 128) * 2;   // 391 node-tiles x 2 col-halves
        k_dense1<<<nblocks, 256, 0, stream>>>(mean, x, b1cat, b1, h);
    }

    // ---- layer 2 ----
    {
        int nblocks = ((N_NODES + 127) / 128) * 2;   // 391 node-tiles x 2 col-halves
        k_dense2<<<nblocks, 256, 0, stream>>>(h, b2cat, b2, z);
    }
    k_gather40<<<(N_NODES + 7) / 8, 320, 0, stream>>>(rowptr, eidx, z, outp);
}

// Round 11
// 203.131 us; speedup vs baseline: 1.3575x; 1.3575x over previous
//
#include <hip/hip_runtime.h>

#define N_NODES 50000
#define E_EDGES 800000
#define SCAN_NBLK 196   // ceil(50000/256)

typedef __attribute__((ext_vector_type(8))) short bf16x8;
typedef __attribute__((ext_vector_type(4))) float f32x4;

__device__ __forceinline__ unsigned short f2bf(float f) {
    unsigned u = __float_as_uint(f);
    u = (u + 0x7FFF + ((u >> 16) & 1)) >> 16;   // RNE
    return (unsigned short)u;
}
__device__ __forceinline__ float bf2f(unsigned short s) {
    return __uint_as_float(((unsigned)s) << 16);
}

// ---------------- CSR build ----------------

__global__ void k_count(const int* __restrict__ dst, int* __restrict__ cnt) {
    int e = blockIdx.x * blockDim.x + threadIdx.x;
    if (e < E_EDGES) atomicAdd(&cnt[dst[e]], 1);
}

__global__ void k_scan_part(const int* __restrict__ cnt, int* __restrict__ excl,
                            int* __restrict__ bsum) {
    __shared__ int sm[256];
    int b = blockIdx.x, t = threadIdx.x;
    int i = b * 256 + t;
    int v = (i < N_NODES) ? cnt[i] : 0;
    sm[t] = v;
    __syncthreads();
    for (int off = 1; off < 256; off <<= 1) {
        int u = (t >= off) ? sm[t - off] : 0;
        __syncthreads();
        sm[t] += u;
        __syncthreads();
    }
    if (i < N_NODES) excl[i] = sm[t] - v;
    if (t == 255) bsum[b] = sm[255];
}

__global__ void k_scan_bsum(const int* __restrict__ bsum, int* __restrict__ boff) {
    __shared__ int sm[256];
    int t = threadIdx.x;
    int v = (t < SCAN_NBLK) ? bsum[t] : 0;
    sm[t] = v;
    __syncthreads();
    for (int off = 1; off < 256; off <<= 1) {
        int u = (t >= off) ? sm[t - off] : 0;
        __syncthreads();
        sm[t] += u;
        __syncthreads();
    }
    if (t < SCAN_NBLK) boff[t] = sm[t] - v;
}

__global__ void k_scan_add(int* __restrict__ rowptr, const int* __restrict__ boff,
                           int* __restrict__ cursor) {
    int b = blockIdx.x, t = threadIdx.x;
    int i = b * 256 + t;
    if (i < N_NODES) {
        int r = rowptr[i] + boff[b];
        rowptr[i] = r;
        cursor[i] = r;
    }
    if (i == 0) rowptr[N_NODES] = E_EDGES;
}

__global__ void k_fill(const int* __restrict__ src, const int* __restrict__ dst,
                       int* __restrict__ cursor, int* __restrict__ eidx) {
    int e = blockIdx.x * blockDim.x + threadIdx.x;
    if (e < E_EDGES) {
        int p = atomicAdd(&cursor[dst[e]], 1);
        eidx[p] = src[e];
    }
}

// ---------------- casts / weight packing ----------------

// xb = bf16(x), vectorized
__global__ void k_cast(const float* __restrict__ x, unsigned short* __restrict__ xb) {
    int tid = blockIdx.x * blockDim.x + threadIdx.x;
    const int total4 = N_NODES * 32;       // float4 groups
    for (int i = tid; i < total4; i += gridDim.x * blockDim.x) {
        float4 v = ((const float4*)x)[i];
        ushort4 o;
        o.x = f2bf(v.x); o.y = f2bf(v.y); o.z = f2bf(v.z); o.w = f2bf(v.w);
        ((ushort4*)xb)[i] = o;
    }
}

// Pack B1 = [W1l.T | W1r.T] (K=256, N=128) into MFMA fragment order:
// frag index (kt,ct,l), elem i: B[k=kt*32+8*(l>>4)+i][c=ct*16+(l&15)] = Wsrc[c][k']
__global__ void k_pack1(const float* __restrict__ W1l, const float* __restrict__ W1r,
                        unsigned short* __restrict__ Bpk) {
    int idx = blockIdx.x * 256 + threadIdx.x;
    if (idx >= 8 * 8 * 64) return;
    int kt = idx >> 9;             // 0..7
    int ct = (idx >> 6) & 7;       // 0..7
    int l  = idx & 63;
    int c  = ct * 16 + (l & 15);
    int k0 = kt * 32 + (l >> 4) * 8;
    const float* Wr = (k0 < 128) ? (W1l + (size_t)c * 128 + k0)
                                 : (W1r + (size_t)c * 128 + (k0 - 128));
    bf16x8 v;
#pragma unroll
    for (int i = 0; i < 8; ++i) v[i] = (short)f2bf(Wr[i]);
    *(bf16x8*)(Bpk + (size_t)idx * 8) = v;
}

// Pack B2 = [W2l.T | W2r.T] (K=128, N=80): frag (kt 0..3, ct 0..4, l)
__global__ void k_pack2(const float* __restrict__ W2l, const float* __restrict__ W2r,
                        unsigned short* __restrict__ Bpk) {
    int idx = blockIdx.x * 256 + threadIdx.x;
    if (idx >= 4 * 5 * 64) return;
    int kt  = idx / 320;
    int rem = idx - kt * 320;
    int ct  = rem >> 6;            // 0..4
    int l   = rem & 63;
    int c   = ct * 16 + (l & 15);
    int k0  = kt * 32 + (l >> 4) * 8;
    const float* Wr = (c < 40) ? (W2l + (size_t)c * 128 + k0)
                               : (W2r + (size_t)(c - 40) * 128 + k0);
    bf16x8 v;
#pragma unroll
    for (int i = 0; i < 8; ++i) v[i] = (short)f2bf(Wr[i]);
    *(bf16x8*)(Bpk + (size_t)idx * 8) = v;
}

// ---------------- gathers ----------------

// meanb[i,:] = bf16( (1/max(deg,1)) * sum_j xb[j,:] )   (fp32 accumulate)
// block 256 thr = 8 nodes x 32 lanes; lane owns 4 features.
__global__ void k_gather128(const int* __restrict__ rowptr, const int* __restrict__ eidx,
                            const unsigned short* __restrict__ xb,
                            unsigned short* __restrict__ meanb) {
    int t = threadIdx.x;
    int i = blockIdx.x * 8 + (t >> 5);
    int g = t & 31;
    if (i >= N_NODES) return;
    int beg = rowptr[i], end = rowptr[i + 1];
    float a0 = 0.f, a1 = 0.f, a2 = 0.f, a3 = 0.f;
    int j = beg;
    for (; j + 3 < end; j += 4) {
        int s0 = eidx[j], s1 = eidx[j + 1], s2 = eidx[j + 2], s3 = eidx[j + 3];
        ushort4 u0 = *(const ushort4*)&xb[(size_t)s0 * 128 + g * 4];
        ushort4 u1 = *(const ushort4*)&xb[(size_t)s1 * 128 + g * 4];
        ushort4 u2 = *(const ushort4*)&xb[(size_t)s2 * 128 + g * 4];
        ushort4 u3 = *(const ushort4*)&xb[(size_t)s3 * 128 + g * 4];
        a0 += bf2f(u0.x) + bf2f(u1.x) + bf2f(u2.x) + bf2f(u3.x);
        a1 += bf2f(u0.y) + bf2f(u1.y) + bf2f(u2.y) + bf2f(u3.y);
        a2 += bf2f(u0.z) + bf2f(u1.z) + bf2f(u2.z) + bf2f(u3.z);
        a3 += bf2f(u0.w) + bf2f(u1.w) + bf2f(u2.w) + bf2f(u3.w);
    }
    for (; j < end; ++j) {
        ushort4 u = *(const ushort4*)&xb[(size_t)eidx[j] * 128 + g * 4];
        a0 += bf2f(u.x); a1 += bf2f(u.y); a2 += bf2f(u.z); a3 += bf2f(u.w);
    }
    float inv = 1.0f / fmaxf((float)(end - beg), 1.0f);
    ushort4 r;
    r.x = f2bf(a0 * inv); r.y = f2bf(a1 * inv);
    r.z = f2bf(a2 * inv); r.w = f2bf(a3 * inv);
    *(ushort4*)&meanb[(size_t)i * 128 + g * 4] = r;
}

// out[i,o] = zr[i,o] + inv * sum_j zl[j,o]
// block 320 thr = 8 nodes x 40 lanes (grid*8 == N exactly)
__global__ void k_gather40(const int* __restrict__ rowptr, const int* __restrict__ eidx,
                           const unsigned short* __restrict__ zl,
                           const float* __restrict__ zr, float* __restrict__ out) {
    int t = threadIdx.x;
    int i = blockIdx.x * 8 + t / 40;
    int o = t % 40;
    int beg = rowptr[i], end = rowptr[i + 1];
    float acc = 0.0f;
    int j = beg;
    for (; j + 3 < end; j += 4) {
        int s0 = eidx[j], s1 = eidx[j + 1], s2 = eidx[j + 2], s3 = eidx[j + 3];
        acc += bf2f(zl[(size_t)s0 * 40 + o]) + bf2f(zl[(size_t)s1 * 40 + o])
             + bf2f(zl[(size_t)s2 * 40 + o]) + bf2f(zl[(size_t)s3 * 40 + o]);
    }
    for (; j < end; ++j)
        acc += bf2f(zl[(size_t)eidx[j] * 40 + o]);
    float inv = 1.0f / fmaxf((float)(end - beg), 1.0f);
    out[(size_t)i * 40 + o] = zr[(size_t)i * 40 + o] + acc * inv;
}

// ---------------- layer 1 dense (MFMA bf16) ----------------
// hb[16-row tile] = relu([meanb|xb] @ B1 + b1), 1 wave per M-tile, 8 c-tiles.
// A-frag: row=l&15, k=8*(l>>4)+i. C/D: col=l&15, row=(l>>4)*4+reg.
__launch_bounds__(64)
__global__ void k_dense1_mfma(const unsigned short* __restrict__ meanb,
                              const unsigned short* __restrict__ xb,
                              const unsigned short* __restrict__ Bpk,
                              const float* __restrict__ b1,
                              unsigned short* __restrict__ hb) {
    int l  = threadIdx.x;          // 0..63
    int mt = blockIdx.x;           // 0..3124 (50000/16 exact)
    int m0 = mt * 16;
    int row = l & 15, kg = l >> 4;

    const unsigned short* mp = meanb + (size_t)(m0 + row) * 128 + kg * 8;
    const unsigned short* xp = xb    + (size_t)(m0 + row) * 128 + kg * 8;

    bf16x8 af[8];
#pragma unroll
    for (int kt = 0; kt < 4; ++kt) af[kt]     = *(const bf16x8*)(mp + kt * 32);
#pragma unroll
    for (int kt = 0; kt < 4; ++kt) af[4 + kt] = *(const bf16x8*)(xp + kt * 32);

    int rbase = m0 + (l >> 4) * 4;

#pragma unroll
    for (int ct = 0; ct < 8; ++ct) {
        f32x4 acc = {0.f, 0.f, 0.f, 0.f};
#pragma unroll
        for (int kt = 0; kt < 8; ++kt)
            acc = __builtin_amdgcn_mfma_f32_16x16x32_bf16(
                      af[kt],
                      *(const bf16x8*)(Bpk + (size_t)((kt * 8 + ct) * 64 + l) * 8),
                      acc, 0, 0, 0);
        int c = ct * 16 + (l & 15);
        float bias = b1[c];
#pragma unroll
        for (int r = 0; r < 4; ++r) {
            float v = fmaxf(acc[r] + bias, 0.0f);
            hb[(size_t)(rbase + r) * 128 + c] = f2bf(v);
        }
    }
}

// ---------------- layer 2 dense (MFMA bf16) ----------------
// z[16-row tile] = hb @ B2 (+b2 on cols>=40); cols<40 -> zl (bf16), >=40 -> zr (f32)
__launch_bounds__(64)
__global__ void k_dense2_mfma(const unsigned short* __restrict__ hb,
                              const unsigned short* __restrict__ Bpk,
                              const float* __restrict__ b2,
                              unsigned short* __restrict__ zl,
                              float* __restrict__ zr) {
    int l  = threadIdx.x;
    int mt = blockIdx.x;
    int m0 = mt * 16;
    int row = l & 15, kg = l >> 4;

    const unsigned short* hp = hb + (size_t)(m0 + row) * 128 + kg * 8;

    bf16x8 af[4];
#pragma unroll
    for (int kt = 0; kt < 4; ++kt) af[kt] = *(const bf16x8*)(hp + kt * 32);

    int rbase = m0 + (l >> 4) * 4;

#pragma unroll
    for (int ct = 0; ct < 5; ++ct) {
        f32x4 acc = {0.f, 0.f, 0.f, 0.f};
#pragma unroll
        for (int kt = 0; kt < 4; ++kt)
            acc = __builtin_amdgcn_mfma_f32_16x16x32_bf16(
                      af[kt],
                      *(const bf16x8*)(Bpk + (size_t)((kt * 5 + ct) * 64 + l) * 8),
                      acc, 0, 0, 0);
        int c = ct * 16 + (l & 15);
        if (c < 40) {
#pragma unroll
            for (int r = 0; r < 4; ++r)
                zl[(size_t)(rbase + r) * 40 + c] = f2bf(acc[r]);
        } else {
            float bias = b2[c - 40];
#pragma unroll
            for (int r = 0; r < 4; ++r)
                zr[(size_t)(rbase + r) * 40 + (c - 40)] = acc[r] + bias;
        }
    }
}

// ---------------- launch ----------------

extern "C" void kernel_launch(void* const* d_in, const int* in_sizes, int n_in,
                              void* d_out, int out_size, void* d_ws, size_t ws_size,
                              hipStream_t stream) {
    const float* x   = (const float*)d_in[0];
    const int*   ei  = (const int*)d_in[1];      // [2, E] int32
    const float* W1l = (const float*)d_in[2];
    const float* b1  = (const float*)d_in[3];
    const float* W1r = (const float*)d_in[4];
    const float* W2l = (const float*)d_in[5];
    const float* b2  = (const float*)d_in[6];
    const float* W2r = (const float*)d_in[7];

    const int* src = ei;
    const int* dst = ei + E_EDGES;

    // ---- workspace carve (16B-aligned) ----
    char* base = (char*)d_ws;
    size_t off = 0;
    auto carve = [&](size_t bytes) {
        void* p = base + off;
        off += (bytes + 15) & ~(size_t)15;
        return p;
    };
    int*   cnt    = (int*)  carve((size_t)N_NODES * 4);
    int*   rowptr = (int*)  carve((size_t)(N_NODES + 1) * 4);
    int*   cursor = (int*)  carve((size_t)N_NODES * 4);
    int*   eidx   = (int*)  carve((size_t)E_EDGES * 4);
    int*   bsum   = (int*)  carve((size_t)256 * 4);
    int*   boff   = (int*)  carve((size_t)256 * 4);
    unsigned short* bpk1  = (unsigned short*)carve((size_t)8 * 8 * 64 * 8 * 2);   // 64 KB
    unsigned short* bpk2  = (unsigned short*)carve((size_t)4 * 5 * 64 * 8 * 2);   // 20 KB
    unsigned short* xb    = (unsigned short*)carve((size_t)N_NODES * 128 * 2);
    unsigned short* meanb = (unsigned short*)carve((size_t)N_NODES * 128 * 2);
    unsigned short* hb    = (unsigned short*)carve((size_t)N_NODES * 128 * 2);
    unsigned short* zl    = (unsigned short*)carve((size_t)N_NODES * 40 * 2);
    float*          zr    = (float*)carve((size_t)N_NODES * 40 * 4);
    float* outp = (float*)d_out;

    // ---- CSR build ----
    hipMemsetAsync(cnt, 0, (size_t)N_NODES * 4, stream);
    k_count<<<(E_EDGES + 255) / 256, 256, 0, stream>>>(dst, cnt);
    k_scan_part<<<SCAN_NBLK, 256, 0, stream>>>(cnt, rowptr, bsum);
    k_scan_bsum<<<1, 256, 0, stream>>>(bsum, boff);
    k_scan_add<<<SCAN_NBLK, 256, 0, stream>>>(rowptr, boff, cursor);
    k_fill<<<(E_EDGES + 255) / 256, 256, 0, stream>>>(src, dst, cursor, eidx);

    // ---- casts + weight packing ----
    k_cast<<<2048, 256, 0, stream>>>(x, xb);
    k_pack1<<<16, 256, 0, stream>>>(W1l, W1r, bpk1);
    k_pack2<<<5, 256, 0, stream>>>(W2l, W2r, bpk2);

    // ---- layer 1 ----
    k_gather128<<<(N_NODES + 7) / 8, 256, 0, stream>>>(rowptr, eidx, xb, meanb);
    k_dense1_mfma<<<N_NODES / 16, 64, 0, stream>>>(meanb, xb, bpk1, b1, hb);

    // ---- layer 2 ----
    k_dense2_mfma<<<N_NODES / 16, 64, 0, stream>>>(hb, bpk2, b2, zl, zr);
    k_gather40<<<(N_NODES + 7) / 8, 320, 0, stream>>>(rowptr, eidx, zl, zr, outp);
}

// Round 12
// 188.161 us; speedup vs baseline: 1.4655x; 1.0796x over previous
//
#include <hip/hip_runtime.h>

#define N_NODES 50000
#define E_EDGES 800000
#define SCAN_NBLK 196   // ceil(50000/256)
#define NSHARD 8
#define SHARD_W (N_NODES / NSHARD)   // 6250

typedef __attribute__((ext_vector_type(8))) short bf16x8;
typedef __attribute__((ext_vector_type(4))) float f32x4;

__device__ __forceinline__ unsigned short f2bf(float f) {
    unsigned u = __float_as_uint(f);
    u = (u + 0x7FFF + ((u >> 16) & 1)) >> 16;   // RNE
    return (unsigned short)u;
}
__device__ __forceinline__ float bf2f(unsigned short s) {
    return __uint_as_float(((unsigned)s) << 16);
}

// ---------------- CSR build ----------------

__global__ void k_count(const int* __restrict__ dst, int* __restrict__ cnt) {
    int e = blockIdx.x * blockDim.x + threadIdx.x;
    if (e < E_EDGES) atomicAdd(&cnt[dst[e]], 1);
}

__global__ void k_scan_part(const int* __restrict__ cnt, int* __restrict__ excl,
                            int* __restrict__ bsum) {
    __shared__ int sm[256];
    int b = blockIdx.x, t = threadIdx.x;
    int i = b * 256 + t;
    int v = (i < N_NODES) ? cnt[i] : 0;
    sm[t] = v;
    __syncthreads();
    for (int off = 1; off < 256; off <<= 1) {
        int u = (t >= off) ? sm[t - off] : 0;
        __syncthreads();
        sm[t] += u;
        __syncthreads();
    }
    if (i < N_NODES) excl[i] = sm[t] - v;
    if (t == 255) bsum[b] = sm[255];
}

__global__ void k_scan_bsum(const int* __restrict__ bsum, int* __restrict__ boff) {
    __shared__ int sm[256];
    int t = threadIdx.x;
    int v = (t < SCAN_NBLK) ? bsum[t] : 0;
    sm[t] = v;
    __syncthreads();
    for (int off = 1; off < 256; off <<= 1) {
        int u = (t >= off) ? sm[t - off] : 0;
        __syncthreads();
        sm[t] += u;
        __syncthreads();
    }
    if (t < SCAN_NBLK) boff[t] = sm[t] - v;
}

__global__ void k_scan_add(int* __restrict__ rowptr, const int* __restrict__ boff,
                           int* __restrict__ cursor) {
    int b = blockIdx.x, t = threadIdx.x;
    int i = b * 256 + t;
    if (i < N_NODES) {
        int r = rowptr[i] + boff[b];
        rowptr[i] = r;
        cursor[i] = r;
    }
    if (i == 0) rowptr[N_NODES] = E_EDGES;
}

// dst-range-sharded fill: shard = blockIdx&7 (XCD round-robin); each shard
// handles dst in [shard*6250, +6250) so all writes to a given eidx line come
// from one XCD's L2 -> full-line assembly, write traffic 51.6MB -> ~4MB.
__global__ void k_fill_shard(const int* __restrict__ src, const int* __restrict__ dst,
                             int* __restrict__ cursor, int* __restrict__ eidx) {
    int shard = blockIdx.x & (NSHARD - 1);
    int chunk = blockIdx.x >> 3;
    int e = chunk * 256 + threadIdx.x;
    if (e >= E_EDGES) return;
    int d = dst[e];
    int lo = shard * SHARD_W;
    if (d >= lo && d < lo + SHARD_W) {
        int p = atomicAdd(&cursor[d], 1);
        eidx[p] = src[e];
    }
}

// ---------------- casts / weight packing ----------------

__global__ void k_cast(const float* __restrict__ x, unsigned short* __restrict__ xb) {
    int tid = blockIdx.x * blockDim.x + threadIdx.x;
    const int total4 = N_NODES * 32;       // float4 groups
    for (int i = tid; i < total4; i += gridDim.x * blockDim.x) {
        float4 v = ((const float4*)x)[i];
        ushort4 o;
        o.x = f2bf(v.x); o.y = f2bf(v.y); o.z = f2bf(v.z); o.w = f2bf(v.w);
        ((ushort4*)xb)[i] = o;
    }
}

// Pack B1 = [W1l.T | W1r.T] (K=256, N=128) into MFMA fragment order
__global__ void k_pack1(const float* __restrict__ W1l, const float* __restrict__ W1r,
                        unsigned short* __restrict__ Bpk) {
    int idx = blockIdx.x * 256 + threadIdx.x;
    if (idx >= 8 * 8 * 64) return;
    int kt = idx >> 9;             // 0..7
    int ct = (idx >> 6) & 7;       // 0..7
    int l  = idx & 63;
    int c  = ct * 16 + (l & 15);
    int k0 = kt * 32 + (l >> 4) * 8;
    const float* Wr = (k0 < 128) ? (W1l + (size_t)c * 128 + k0)
                                 : (W1r + (size_t)c * 128 + (k0 - 128));
    bf16x8 v;
#pragma unroll
    for (int i = 0; i < 8; ++i) v[i] = (short)f2bf(Wr[i]);
    *(bf16x8*)(Bpk + (size_t)idx * 8) = v;
}

// Pack B2 = [W2l.T | W2r.T] (K=128, N=80): frag (kt 0..3, ct 0..4, l)
__global__ void k_pack2(const float* __restrict__ W2l, const float* __restrict__ W2r,
                        unsigned short* __restrict__ Bpk) {
    int idx = blockIdx.x * 256 + threadIdx.x;
    if (idx >= 4 * 5 * 64) return;
    int kt  = idx / 320;
    int rem = idx - kt * 320;
    int ct  = rem >> 6;            // 0..4
    int l   = rem & 63;
    int c   = ct * 16 + (l & 15);
    int k0  = kt * 32 + (l >> 4) * 8;
    const float* Wr = (c < 40) ? (W2l + (size_t)c * 128 + k0)
                               : (W2r + (size_t)(c - 40) * 128 + k0);
    bf16x8 v;
#pragma unroll
    for (int i = 0; i < 8; ++i) v[i] = (short)f2bf(Wr[i]);
    *(bf16x8*)(Bpk + (size_t)idx * 8) = v;
}

// ---------------- gathers ----------------

// meanb[i,:] = bf16( (1/max(deg,1)) * sum_j xb[j,:] )   (fp32 accumulate)
__global__ void k_gather128(const int* __restrict__ rowptr, const int* __restrict__ eidx,
                            const unsigned short* __restrict__ xb,
                            unsigned short* __restrict__ meanb) {
    int t = threadIdx.x;
    int i = blockIdx.x * 8 + (t >> 5);
    int g = t & 31;
    if (i >= N_NODES) return;
    int beg = rowptr[i], end = rowptr[i + 1];
    float a0 = 0.f, a1 = 0.f, a2 = 0.f, a3 = 0.f;
    int j = beg;
    for (; j + 3 < end; j += 4) {
        int s0 = eidx[j], s1 = eidx[j + 1], s2 = eidx[j + 2], s3 = eidx[j + 3];
        ushort4 u0 = *(const ushort4*)&xb[(size_t)s0 * 128 + g * 4];
        ushort4 u1 = *(const ushort4*)&xb[(size_t)s1 * 128 + g * 4];
        ushort4 u2 = *(const ushort4*)&xb[(size_t)s2 * 128 + g * 4];
        ushort4 u3 = *(const ushort4*)&xb[(size_t)s3 * 128 + g * 4];
        a0 += bf2f(u0.x) + bf2f(u1.x) + bf2f(u2.x) + bf2f(u3.x);
        a1 += bf2f(u0.y) + bf2f(u1.y) + bf2f(u2.y) + bf2f(u3.y);
        a2 += bf2f(u0.z) + bf2f(u1.z) + bf2f(u2.z) + bf2f(u3.z);
        a3 += bf2f(u0.w) + bf2f(u1.w) + bf2f(u2.w) + bf2f(u3.w);
    }
    for (; j < end; ++j) {
        ushort4 u = *(const ushort4*)&xb[(size_t)eidx[j] * 128 + g * 4];
        a0 += bf2f(u.x); a1 += bf2f(u.y); a2 += bf2f(u.z); a3 += bf2f(u.w);
    }
    float inv = 1.0f / fmaxf((float)(end - beg), 1.0f);
    ushort4 r;
    r.x = f2bf(a0 * inv); r.y = f2bf(a1 * inv);
    r.z = f2bf(a2 * inv); r.w = f2bf(a3 * inv);
    *(ushort4*)&meanb[(size_t)i * 128 + g * 4] = r;
}

// out[i,o] = zr[i,o] + inv * sum_j zl[j,o]
__global__ void k_gather40(const int* __restrict__ rowptr, const int* __restrict__ eidx,
                           const unsigned short* __restrict__ zl,
                           const float* __restrict__ zr, float* __restrict__ out) {
    int t = threadIdx.x;
    int i = blockIdx.x * 8 + t / 40;
    int o = t % 40;
    int beg = rowptr[i], end = rowptr[i + 1];
    float acc = 0.0f;
    int j = beg;
    for (; j + 3 < end; j += 4) {
        int s0 = eidx[j], s1 = eidx[j + 1], s2 = eidx[j + 2], s3 = eidx[j + 3];
        acc += bf2f(zl[(size_t)s0 * 40 + o]) + bf2f(zl[(size_t)s1 * 40 + o])
             + bf2f(zl[(size_t)s2 * 40 + o]) + bf2f(zl[(size_t)s3 * 40 + o]);
    }
    for (; j < end; ++j)
        acc += bf2f(zl[(size_t)eidx[j] * 40 + o]);
    float inv = 1.0f / fmaxf((float)(end - beg), 1.0f);
    out[(size_t)i * 40 + o] = zr[(size_t)i * 40 + o] + acc * inv;
}

// ---------------- layer 1 dense (MFMA bf16) ----------------
__launch_bounds__(64)
__global__ void k_dense1_mfma(const unsigned short* __restrict__ meanb,
                              const unsigned short* __restrict__ xb,
                              const unsigned short* __restrict__ Bpk,
                              const float* __restrict__ b1,
                              unsigned short* __restrict__ hb) {
    int l  = threadIdx.x;          // 0..63
    int mt = blockIdx.x;           // 0..3124
    int m0 = mt * 16;
    int row = l & 15, kg = l >> 4;

    const unsigned short* mp = meanb + (size_t)(m0 + row) * 128 + kg * 8;
    const unsigned short* xp = xb    + (size_t)(m0 + row) * 128 + kg * 8;

    bf16x8 af[8];
#pragma unroll
    for (int kt = 0; kt < 4; ++kt) af[kt]     = *(const bf16x8*)(mp + kt * 32);
#pragma unroll
    for (int kt = 0; kt < 4; ++kt) af[4 + kt] = *(const bf16x8*)(xp + kt * 32);

    int rbase = m0 + (l >> 4) * 4;

#pragma unroll
    for (int ct = 0; ct < 8; ++ct) {
        f32x4 acc = {0.f, 0.f, 0.f, 0.f};
#pragma unroll
        for (int kt = 0; kt < 8; ++kt)
            acc = __builtin_amdgcn_mfma_f32_16x16x32_bf16(
                      af[kt],
                      *(const bf16x8*)(Bpk + (size_t)((kt * 8 + ct) * 64 + l) * 8),
                      acc, 0, 0, 0);
        int c = ct * 16 + (l & 15);
        float bias = b1[c];
#pragma unroll
        for (int r = 0; r < 4; ++r) {
            float v = fmaxf(acc[r] + bias, 0.0f);
            hb[(size_t)(rbase + r) * 128 + c] = f2bf(v);
        }
    }
}

// ---------------- layer 2 dense (MFMA bf16) ----------------
__launch_bounds__(64)
__global__ void k_dense2_mfma(const unsigned short* __restrict__ hb,
                              const unsigned short* __restrict__ Bpk,
                              const float* __restrict__ b2,
                              unsigned short* __restrict__ zl,
                              float* __restrict__ zr) {
    int l  = threadIdx.x;
    int mt = blockIdx.x;
    int m0 = mt * 16;
    int row = l & 15, kg = l >> 4;

    const unsigned short* hp = hb + (size_t)(m0 + row) * 128 + kg * 8;

    bf16x8 af[4];
#pragma unroll
    for (int kt = 0; kt < 4; ++kt) af[kt] = *(const bf16x8*)(hp + kt * 32);

    int rbase = m0 + (l >> 4) * 4;

#pragma unroll
    for (int ct = 0; ct < 5; ++ct) {
        f32x4 acc = {0.f, 0.f, 0.f, 0.f};
#pragma unroll
        for (int kt = 0; kt < 4; ++kt)
            acc = __builtin_amdgcn_mfma_f32_16x16x32_bf16(
                      af[kt],
                      *(const bf16x8*)(Bpk + (size_t)((kt * 5 + ct) * 64 + l) * 8),
                      acc, 0, 0, 0);
        int c = ct * 16 + (l & 15);
        if (c < 40) {
#pragma unroll
            for (int r = 0; r < 4; ++r)
                zl[(size_t)(rbase + r) * 40 + c] = f2bf(acc[r]);
        } else {
            float bias = b2[c - 40];
#pragma unroll
            for (int r = 0; r < 4; ++r)
                zr[(size_t)(rbase + r) * 40 + (c - 40)] = acc[r] + bias;
        }
    }
}

// ---------------- launch ----------------

extern "C" void kernel_launch(void* const* d_in, const int* in_sizes, int n_in,
                              void* d_out, int out_size, void* d_ws, size_t ws_size,
                              hipStream_t stream) {
    const float* x   = (const float*)d_in[0];
    const int*   ei  = (const int*)d_in[1];      // [2, E] int32
    const float* W1l = (const float*)d_in[2];
    const float* b1  = (const float*)d_in[3];
    const float* W1r = (const float*)d_in[4];
    const float* W2l = (const float*)d_in[5];
    const float* b2  = (const float*)d_in[6];
    const float* W2r = (const float*)d_in[7];

    const int* src = ei;
    const int* dst = ei + E_EDGES;

    // ---- workspace carve (16B-aligned) ----
    char* base = (char*)d_ws;
    size_t off = 0;
    auto carve = [&](size_t bytes) {
        void* p = base + off;
        off += (bytes + 15) & ~(size_t)15;
        return p;
    };
    int*   cnt    = (int*)  carve((size_t)N_NODES * 4);
    int*   rowptr = (int*)  carve((size_t)(N_NODES + 1) * 4);
    int*   cursor = (int*)  carve((size_t)N_NODES * 4);
    int*   eidx   = (int*)  carve((size_t)E_EDGES * 4);
    int*   bsum   = (int*)  carve((size_t)256 * 4);
    int*   boff   = (int*)  carve((size_t)256 * 4);
    unsigned short* bpk1  = (unsigned short*)carve((size_t)8 * 8 * 64 * 8 * 2);   // 64 KB
    unsigned short* bpk2  = (unsigned short*)carve((size_t)4 * 5 * 64 * 8 * 2);   // 20 KB
    unsigned short* xb    = (unsigned short*)carve((size_t)N_NODES * 128 * 2);
    unsigned short* meanb = (unsigned short*)carve((size_t)N_NODES * 128 * 2);
    unsigned short* hb    = (unsigned short*)carve((size_t)N_NODES * 128 * 2);
    unsigned short* zl    = (unsigned short*)carve((size_t)N_NODES * 40 * 2);
    float*          zr    = (float*)carve((size_t)N_NODES * 40 * 4);
    float* outp = (float*)d_out;

    // ---- CSR build ----
    hipMemsetAsync(cnt, 0, (size_t)N_NODES * 4, stream);
    k_count<<<(E_EDGES + 255) / 256, 256, 0, stream>>>(dst, cnt);
    k_scan_part<<<SCAN_NBLK, 256, 0, stream>>>(cnt, rowptr, bsum);
    k_scan_bsum<<<1, 256, 0, stream>>>(bsum, boff);
    k_scan_add<<<SCAN_NBLK, 256, 0, stream>>>(rowptr, boff, cursor);
    {
        int chunks = (E_EDGES + 255) / 256;           // 3125
        k_fill_shard<<<chunks * NSHARD, 256, 0, stream>>>(src, dst, cursor, eidx);
    }

    // ---- casts + weight packing ----
    k_cast<<<2048, 256, 0, stream>>>(x, xb);
    k_pack1<<<16, 256, 0, stream>>>(W1l, W1r, bpk1);
    k_pack2<<<5, 256, 0, stream>>>(W2l, W2r, bpk2);

    // ---- layer 1 ----
    k_gather128<<<(N_NODES + 7) / 8, 256, 0, stream>>>(rowptr, eidx, xb, meanb);
    k_dense1_mfma<<<N_NODES / 16, 64, 0, stream>>>(meanb, xb, bpk1, b1, hb);

    // ---- layer 2 ----
    k_dense2_mfma<<<N_NODES / 16, 64, 0, stream>>>(hb, bpk2, b2, zl, zr);
    k_gather40<<<(N_NODES + 7) / 8, 320, 0, stream>>>(rowptr, eidx, zl, zr, outp);
}

// Round 13
// 187.853 us; speedup vs baseline: 1.4679x; 1.0016x over previous
//
#include <hip/hip_runtime.h>

#define N_NODES 50000
#define E_EDGES 800000
#define SCAN_NBLK 196   // ceil(50000/256)
#define NSHARD 8
#define SHARD_W (N_NODES / NSHARD)   // 6250

typedef __attribute__((ext_vector_type(8))) short bf16x8;
typedef __attribute__((ext_vector_type(4))) float f32x4;

__device__ __forceinline__ unsigned short f2bf(float f) {
    unsigned u = __float_as_uint(f);
    u = (u + 0x7FFF + ((u >> 16) & 1)) >> 16;   // RNE
    return (unsigned short)u;
}
__device__ __forceinline__ float bf2f(unsigned short s) {
    return __uint_as_float(((unsigned)s) << 16);
}

// ---------------- CSR build ----------------

__global__ void k_count(const int* __restrict__ dst, int* __restrict__ cnt) {
    int e = blockIdx.x * blockDim.x + threadIdx.x;
    if (e < E_EDGES) atomicAdd(&cnt[dst[e]], 1);
}

__global__ void k_scan_part(const int* __restrict__ cnt, int* __restrict__ excl,
                            int* __restrict__ bsum) {
    __shared__ int sm[256];
    int b = blockIdx.x, t = threadIdx.x;
    int i = b * 256 + t;
    int v = (i < N_NODES) ? cnt[i] : 0;
    sm[t] = v;
    __syncthreads();
    for (int off = 1; off < 256; off <<= 1) {
        int u = (t >= off) ? sm[t - off] : 0;
        __syncthreads();
        sm[t] += u;
        __syncthreads();
    }
    if (i < N_NODES) excl[i] = sm[t] - v;
    if (t == 255) bsum[b] = sm[255];
}

__global__ void k_scan_bsum(const int* __restrict__ bsum, int* __restrict__ boff) {
    __shared__ int sm[256];
    int t = threadIdx.x;
    int v = (t < SCAN_NBLK) ? bsum[t] : 0;
    sm[t] = v;
    __syncthreads();
    for (int off = 1; off < 256; off <<= 1) {
        int u = (t >= off) ? sm[t - off] : 0;
        __syncthreads();
        sm[t] += u;
        __syncthreads();
    }
    if (t < SCAN_NBLK) boff[t] = sm[t] - v;
}

__global__ void k_scan_add(int* __restrict__ rowptr, const int* __restrict__ boff,
                           int* __restrict__ cursor) {
    int b = blockIdx.x, t = threadIdx.x;
    int i = b * 256 + t;
    if (i < N_NODES) {
        int r = rowptr[i] + boff[b];
        rowptr[i] = r;
        cursor[i] = r;
    }
    if (i == 0) rowptr[N_NODES] = E_EDGES;
}

// dst-range-sharded fill: shard = blockIdx&7 (XCD round-robin); each shard
// handles dst in [shard*6250, +6250) so all writes to a given eidx line come
// from one XCD's L2 -> full-line assembly, write traffic 51.6MB -> ~4MB.
__global__ void k_fill_shard(const int* __restrict__ src, const int* __restrict__ dst,
                             int* __restrict__ cursor, int* __restrict__ eidx) {
    int shard = blockIdx.x & (NSHARD - 1);
    int chunk = blockIdx.x >> 3;
    int e = chunk * 256 + threadIdx.x;
    if (e >= E_EDGES) return;
    int d = dst[e];
    int lo = shard * SHARD_W;
    if (d >= lo && d < lo + SHARD_W) {
        int p = atomicAdd(&cursor[d], 1);
        eidx[p] = src[e];
    }
}

// ---------------- casts / weight packing ----------------

__global__ void k_cast(const float* __restrict__ x, unsigned short* __restrict__ xb) {
    int tid = blockIdx.x * blockDim.x + threadIdx.x;
    const int total4 = N_NODES * 32;       // float4 groups
    for (int i = tid; i < total4; i += gridDim.x * blockDim.x) {
        float4 v = ((const float4*)x)[i];
        ushort4 o;
        o.x = f2bf(v.x); o.y = f2bf(v.y); o.z = f2bf(v.z); o.w = f2bf(v.w);
        ((ushort4*)xb)[i] = o;
    }
}

// Pack B1 = [W1l.T | W1r.T] (K=256, N=128) into MFMA fragment order
__global__ void k_pack1(const float* __restrict__ W1l, const float* __restrict__ W1r,
                        unsigned short* __restrict__ Bpk) {
    int idx = blockIdx.x * 256 + threadIdx.x;
    if (idx >= 8 * 8 * 64) return;
    int kt = idx >> 9;             // 0..7
    int ct = (idx >> 6) & 7;       // 0..7
    int l  = idx & 63;
    int c  = ct * 16 + (l & 15);
    int k0 = kt * 32 + (l >> 4) * 8;
    const float* Wr = (k0 < 128) ? (W1l + (size_t)c * 128 + k0)
                                 : (W1r + (size_t)c * 128 + (k0 - 128));
    bf16x8 v;
#pragma unroll
    for (int i = 0; i < 8; ++i) v[i] = (short)f2bf(Wr[i]);
    *(bf16x8*)(Bpk + (size_t)idx * 8) = v;
}

// Pack B2 = [W2l.T | W2r.T] (K=128, N=80): frag (kt 0..3, ct 0..4, l)
__global__ void k_pack2(const float* __restrict__ W2l, const float* __restrict__ W2r,
                        unsigned short* __restrict__ Bpk) {
    int idx = blockIdx.x * 256 + threadIdx.x;
    if (idx >= 4 * 5 * 64) return;
    int kt  = idx / 320;
    int rem = idx - kt * 320;
    int ct  = rem >> 6;            // 0..4
    int l   = rem & 63;
    int c   = ct * 16 + (l & 15);
    int k0  = kt * 32 + (l >> 4) * 8;
    const float* Wr = (c < 40) ? (W2l + (size_t)c * 128 + k0)
                               : (W2r + (size_t)(c - 40) * 128 + k0);
    bf16x8 v;
#pragma unroll
    for (int i = 0; i < 8; ++i) v[i] = (short)f2bf(Wr[i]);
    *(bf16x8*)(Bpk + (size_t)idx * 8) = v;
}

// ---------------- gathers ----------------

// meanb[i,:] = bf16( (1/max(deg,1)) * sum_j xb[j,:] )   (fp32 accumulate)
__global__ void k_gather128(const int* __restrict__ rowptr, const int* __restrict__ eidx,
                            const unsigned short* __restrict__ xb,
                            unsigned short* __restrict__ meanb) {
    int t = threadIdx.x;
    int i = blockIdx.x * 8 + (t >> 5);
    int g = t & 31;
    if (i >= N_NODES) return;
    int beg = rowptr[i], end = rowptr[i + 1];
    float a0 = 0.f, a1 = 0.f, a2 = 0.f, a3 = 0.f;
    int j = beg;
    for (; j + 3 < end; j += 4) {
        int s0 = eidx[j], s1 = eidx[j + 1], s2 = eidx[j + 2], s3 = eidx[j + 3];
        ushort4 u0 = *(const ushort4*)&xb[(size_t)s0 * 128 + g * 4];
        ushort4 u1 = *(const ushort4*)&xb[(size_t)s1 * 128 + g * 4];
        ushort4 u2 = *(const ushort4*)&xb[(size_t)s2 * 128 + g * 4];
        ushort4 u3 = *(const ushort4*)&xb[(size_t)s3 * 128 + g * 4];
        a0 += bf2f(u0.x) + bf2f(u1.x) + bf2f(u2.x) + bf2f(u3.x);
        a1 += bf2f(u0.y) + bf2f(u1.y) + bf2f(u2.y) + bf2f(u3.y);
        a2 += bf2f(u0.z) + bf2f(u1.z) + bf2f(u2.z) + bf2f(u3.z);
        a3 += bf2f(u0.w) + bf2f(u1.w) + bf2f(u2.w) + bf2f(u3.w);
    }
    for (; j < end; ++j) {
        ushort4 u = *(const ushort4*)&xb[(size_t)eidx[j] * 128 + g * 4];
        a0 += bf2f(u.x); a1 += bf2f(u.y); a2 += bf2f(u.z); a3 += bf2f(u.w);
    }
    float inv = 1.0f / fmaxf((float)(end - beg), 1.0f);
    ushort4 r;
    r.x = f2bf(a0 * inv); r.y = f2bf(a1 * inv);
    r.z = f2bf(a2 * inv); r.w = f2bf(a3 * inv);
    *(ushort4*)&meanb[(size_t)i * 128 + g * 4] = r;
}

// out[i,o] = zr[i,o] + inv * sum_j zl[j,o]
__global__ void k_gather40(const int* __restrict__ rowptr, const int* __restrict__ eidx,
                           const unsigned short* __restrict__ zl,
                           const float* __restrict__ zr, float* __restrict__ out) {
    int t = threadIdx.x;
    int i = blockIdx.x * 8 + t / 40;
    int o = t % 40;
    int beg = rowptr[i], end = rowptr[i + 1];
    float acc = 0.0f;
    int j = beg;
    for (; j + 3 < end; j += 4) {
        int s0 = eidx[j], s1 = eidx[j + 1], s2 = eidx[j + 2], s3 = eidx[j + 3];
        acc += bf2f(zl[(size_t)s0 * 40 + o]) + bf2f(zl[(size_t)s1 * 40 + o])
             + bf2f(zl[(size_t)s2 * 40 + o]) + bf2f(zl[(size_t)s3 * 40 + o]);
    }
    for (; j < end; ++j)
        acc += bf2f(zl[(size_t)eidx[j] * 40 + o]);
    float inv = 1.0f / fmaxf((float)(end - beg), 1.0f);
    out[(size_t)i * 40 + o] = zr[(size_t)i * 40 + o] + acc * inv;
}

// ---------------- layer 1 dense (MFMA bf16) ----------------
__launch_bounds__(64)
__global__ void k_dense1_mfma(const unsigned short* __restrict__ meanb,
                              const unsigned short* __restrict__ xb,
                              const unsigned short* __restrict__ Bpk,
                              const float* __restrict__ b1,
                              unsigned short* __restrict__ hb) {
    int l  = threadIdx.x;          // 0..63
    int mt = blockIdx.x;           // 0..3124
    int m0 = mt * 16;
    int row = l & 15, kg = l >> 4;

    const unsigned short* mp = meanb + (size_t)(m0 + row) * 128 + kg * 8;
    const unsigned short* xp = xb    + (size_t)(m0 + row) * 128 + kg * 8;

    bf16x8 af[8];
#pragma unroll
    for (int kt = 0; kt < 4; ++kt) af[kt]     = *(const bf16x8*)(mp + kt * 32);
#pragma unroll
    for (int kt = 0; kt < 4; ++kt) af[4 + kt] = *(const bf16x8*)(xp + kt * 32);

    int rbase = m0 + (l >> 4) * 4;

#pragma unroll
    for (int ct = 0; ct < 8; ++ct) {
        f32x4 acc = {0.f, 0.f, 0.f, 0.f};
#pragma unroll
        for (int kt = 0; kt < 8; ++kt)
            acc = __builtin_amdgcn_mfma_f32_16x16x32_bf16(
                      af[kt],
                      *(const bf16x8*)(Bpk + (size_t)((kt * 8 + ct) * 64 + l) * 8),
                      acc, 0, 0, 0);
        int c = ct * 16 + (l & 15);
        float bias = b1[c];
#pragma unroll
        for (int r = 0; r < 4; ++r) {
            float v = fmaxf(acc[r] + bias, 0.0f);
            hb[(size_t)(rbase + r) * 128 + c] = f2bf(v);
        }
    }
}

// ---------------- layer 2 dense (MFMA bf16) ----------------
__launch_bounds__(64)
__global__ void k_dense2_mfma(const unsigned short* __restrict__ hb,
                              const unsigned short* __restrict__ Bpk,
                              const float* __restrict__ b2,
                              unsigned short* __restrict__ zl,
                              float* __restrict__ zr) {
    int l  = threadIdx.x;
    int mt = blockIdx.x;
    int m0 = mt * 16;
    int row = l & 15, kg = l >> 4;

    const unsigned short* hp = hb + (size_t)(m0 + row) * 128 + kg * 8;

    bf16x8 af[4];
#pragma unroll
    for (int kt = 0; kt < 4; ++kt) af[kt] = *(const bf16x8*)(hp + kt * 32);

    int rbase = m0 + (l >> 4) * 4;

#pragma unroll
    for (int ct = 0; ct < 5; ++ct) {
        f32x4 acc = {0.f, 0.f, 0.f, 0.f};
#pragma unroll
        for (int kt = 0; kt < 4; ++kt)
            acc = __builtin_amdgcn_mfma_f32_16x16x32_bf16(
                      af[kt],
                      *(const bf16x8*)(Bpk + (size_t)((kt * 5 + ct) * 64 + l) * 8),
                      acc, 0, 0, 0);
        int c = ct * 16 + (l & 15);
        if (c < 40) {
#pragma unroll
            for (int r = 0; r < 4; ++r)
                zl[(size_t)(rbase + r) * 40 + c] = f2bf(acc[r]);
        } else {
            float bias = b2[c - 40];
#pragma unroll
            for (int r = 0; r < 4; ++r)
                zr[(size_t)(rbase + r) * 40 + (c - 40)] = acc[r] + bias;
        }
    }
}

// ---------------- launch ----------------

extern "C" void kernel_launch(void* const* d_in, const int* in_sizes, int n_in,
                              void* d_out, int out_size, void* d_ws, size_t ws_size,
                              hipStream_t stream) {
    const float* x   = (const float*)d_in[0];
    const int*   ei  = (const int*)d_in[1];      // [2, E] int32
    const float* W1l = (const float*)d_in[2];
    const float* b1  = (const float*)d_in[3];
    const float* W1r = (const float*)d_in[4];
    const float* W2l = (const float*)d_in[5];
    const float* b2  = (const float*)d_in[6];
    const float* W2r = (const float*)d_in[7];

    const int* src = ei;
    const int* dst = ei + E_EDGES;

    // ---- workspace carve (16B-aligned) ----
    char* base = (char*)d_ws;
    size_t off = 0;
    auto carve = [&](size_t bytes) {
        void* p = base + off;
        off += (bytes + 15) & ~(size_t)15;
        return p;
    };
    int*   cnt    = (int*)  carve((size_t)N_NODES * 4);
    int*   rowptr = (int*)  carve((size_t)(N_NODES + 1) * 4);
    int*   cursor = (int*)  carve((size_t)N_NODES * 4);
    int*   eidx   = (int*)  carve((size_t)E_EDGES * 4);
    int*   bsum   = (int*)  carve((size_t)256 * 4);
    int*   boff   = (int*)  carve((size_t)256 * 4);
    unsigned short* bpk1  = (unsigned short*)carve((size_t)8 * 8 * 64 * 8 * 2);   // 64 KB
    unsigned short* bpk2  = (unsigned short*)carve((size_t)4 * 5 * 64 * 8 * 2);   // 20 KB
    unsigned short* xb    = (unsigned short*)carve((size_t)N_NODES * 128 * 2);
    unsigned short* meanb = (unsigned short*)carve((size_t)N_NODES * 128 * 2);
    unsigned short* hb    = (unsigned short*)carve((size_t)N_NODES * 128 * 2);
    unsigned short* zl    = (unsigned short*)carve((size_t)N_NODES * 40 * 2);
    float*          zr    = (float*)carve((size_t)N_NODES * 40 * 4);
    float* outp = (float*)d_out;

    // ---- CSR build ----
    hipMemsetAsync(cnt, 0, (size_t)N_NODES * 4, stream);
    k_count<<<(E_EDGES + 255) / 256, 256, 0, stream>>>(dst, cnt);
    k_scan_part<<<SCAN_NBLK, 256, 0, stream>>>(cnt, rowptr, bsum);
    k_scan_bsum<<<1, 256, 0, stream>>>(bsum, boff);
    k_scan_add<<<SCAN_NBLK, 256, 0, stream>>>(rowptr, boff, cursor);
    {
        int chunks = (E_EDGES + 255) / 256;           // 3125
        k_fill_shard<<<chunks * NSHARD, 256, 0, stream>>>(src, dst, cursor, eidx);
    }

    // ---- casts + weight packing ----
    k_cast<<<2048, 256, 0, stream>>>(x, xb);
    k_pack1<<<16, 256, 0, stream>>>(W1l, W1r, bpk1);
    k_pack2<<<5, 256, 0, stream>>>(W2l, W2r, bpk2);

    // ---- layer 1 ----
    k_gather128<<<(N_NODES + 7) / 8, 256, 0, stream>>>(rowptr, eidx, xb, meanb);
    k_dense1_mfma<<<N_NODES / 16, 64, 0, stream>>>(meanb, xb, bpk1, b1, hb);

    // ---- layer 2 ----
    k_dense2_mfma<<<N_NODES / 16, 64, 0, stream>>>(hb, bpk2, b2, zl, zr);
    k_gather40<<<(N_NODES + 7) / 8, 320, 0, stream>>>(rowptr, eidx, zl, zr, outp);
}

// Round 14
// 186.145 us; speedup vs baseline: 1.4814x; 1.0092x over previous
//
#include <hip/hip_runtime.h>

#define N_NODES 50000
#define E_EDGES 800000
#define SCAN_NBLK 196   // ceil(50000/256)
#define NSHARD 8
#define SHARD_W (N_NODES / NSHARD)   // 6250

typedef __attribute__((ext_vector_type(8))) short bf16x8;
typedef __attribute__((ext_vector_type(4))) float f32x4;

__device__ __forceinline__ unsigned short f2bf(float f) {
    unsigned u = __float_as_uint(f);
    u = (u + 0x7FFF + ((u >> 16) & 1)) >> 16;   // RNE
    return (unsigned short)u;
}
__device__ __forceinline__ float bf2f(unsigned short s) {
    return __uint_as_float(((unsigned)s) << 16);
}

// ---------------- CSR build ----------------

// replaces hipMemsetAsync(cnt): the rocclr fill kernel measured 42us/replay
// for this 200KB buffer (latency-bound tiny grid); this takes ~3us.
__global__ void k_zero(int* __restrict__ cnt) {
    int i = blockIdx.x * blockDim.x + threadIdx.x;
    if (i < N_NODES) cnt[i] = 0;
}

__global__ void k_count(const int* __restrict__ dst, int* __restrict__ cnt) {
    int e = blockIdx.x * blockDim.x + threadIdx.x;
    if (e < E_EDGES) atomicAdd(&cnt[dst[e]], 1);
}

__global__ void k_scan_part(const int* __restrict__ cnt, int* __restrict__ excl,
                            int* __restrict__ bsum) {
    __shared__ int sm[256];
    int b = blockIdx.x, t = threadIdx.x;
    int i = b * 256 + t;
    int v = (i < N_NODES) ? cnt[i] : 0;
    sm[t] = v;
    __syncthreads();
    for (int off = 1; off < 256; off <<= 1) {
        int u = (t >= off) ? sm[t - off] : 0;
        __syncthreads();
        sm[t] += u;
        __syncthreads();
    }
    if (i < N_NODES) excl[i] = sm[t] - v;
    if (t == 255) bsum[b] = sm[255];
}

__global__ void k_scan_bsum(const int* __restrict__ bsum, int* __restrict__ boff) {
    __shared__ int sm[256];
    int t = threadIdx.x;
    int v = (t < SCAN_NBLK) ? bsum[t] : 0;
    sm[t] = v;
    __syncthreads();
    for (int off = 1; off < 256; off <<= 1) {
        int u = (t >= off) ? sm[t - off] : 0;
        __syncthreads();
        sm[t] += u;
        __syncthreads();
    }
    if (t < SCAN_NBLK) boff[t] = sm[t] - v;
}

__global__ void k_scan_add(int* __restrict__ rowptr, const int* __restrict__ boff,
                           int* __restrict__ cursor) {
    int b = blockIdx.x, t = threadIdx.x;
    int i = b * 256 + t;
    if (i < N_NODES) {
        int r = rowptr[i] + boff[b];
        rowptr[i] = r;
        cursor[i] = r;
    }
    if (i == 0) rowptr[N_NODES] = E_EDGES;
}

// dst-range-sharded fill (shard = blockIdx&7 -> XCD round-robin): all writes
// to a given eidx line assemble within one XCD's L2 -> ~full-line writeback.
__global__ void k_fill_shard(const int* __restrict__ src, const int* __restrict__ dst,
                             int* __restrict__ cursor, int* __restrict__ eidx) {
    int shard = blockIdx.x & (NSHARD - 1);
    int chunk = blockIdx.x >> 3;
    int e = chunk * 256 + threadIdx.x;
    if (e >= E_EDGES) return;
    int d = dst[e];
    int lo = shard * SHARD_W;
    if (d >= lo && d < lo + SHARD_W) {
        int p = atomicAdd(&cursor[d], 1);
        eidx[p] = src[e];
    }
}

// ---------------- casts / weight packing ----------------

__global__ void k_cast(const float* __restrict__ x, unsigned short* __restrict__ xb) {
    int tid = blockIdx.x * blockDim.x + threadIdx.x;
    const int total4 = N_NODES * 32;       // float4 groups
    for (int i = tid; i < total4; i += gridDim.x * blockDim.x) {
        float4 v = ((const float4*)x)[i];
        ushort4 o;
        o.x = f2bf(v.x); o.y = f2bf(v.y); o.z = f2bf(v.z); o.w = f2bf(v.w);
        ((ushort4*)xb)[i] = o;
    }
}

// Pack B1 = [W1l.T | W1r.T] (K=256,N=128) and B2 = [W2l.T | W2r.T] (K=128,N=80)
// into MFMA fragment order, one kernel.
// idx < 4096: B1 frag (kt 0..7, ct 0..7, l). idx >= 4096: B2 frag (kt 0..3, ct 0..4, l).
__global__ void k_pack(const float* __restrict__ W1l, const float* __restrict__ W1r,
                       const float* __restrict__ W2l, const float* __restrict__ W2r,
                       unsigned short* __restrict__ Bpk1,
                       unsigned short* __restrict__ Bpk2) {
    int idx = blockIdx.x * 256 + threadIdx.x;
    if (idx < 8 * 8 * 64) {
        int kt = idx >> 9;             // 0..7
        int ct = (idx >> 6) & 7;       // 0..7
        int l  = idx & 63;
        int c  = ct * 16 + (l & 15);
        int k0 = kt * 32 + (l >> 4) * 8;
        const float* Wr = (k0 < 128) ? (W1l + (size_t)c * 128 + k0)
                                     : (W1r + (size_t)c * 128 + (k0 - 128));
        bf16x8 v;
#pragma unroll
        for (int i = 0; i < 8; ++i) v[i] = (short)f2bf(Wr[i]);
        *(bf16x8*)(Bpk1 + (size_t)idx * 8) = v;
    } else if (idx < 8 * 8 * 64 + 4 * 5 * 64) {
        int j = idx - 8 * 8 * 64;
        int kt  = j / 320;
        int rem = j - kt * 320;
        int ct  = rem >> 6;            // 0..4
        int l   = rem & 63;
        int c   = ct * 16 + (l & 15);
        int k0  = kt * 32 + (l >> 4) * 8;
        const float* Wr = (c < 40) ? (W2l + (size_t)c * 128 + k0)
                                   : (W2r + (size_t)(c - 40) * 128 + k0);
        bf16x8 v;
#pragma unroll
        for (int i = 0; i < 8; ++i) v[i] = (short)f2bf(Wr[i]);
        *(bf16x8*)(Bpk2 + (size_t)j * 8) = v;
    }
}

// ---------------- gathers ----------------

// meanb[i,:] = bf16( (1/max(deg,1)) * sum_j xb[j,:] )   (fp32 accumulate)
__global__ void k_gather128(const int* __restrict__ rowptr, const int* __restrict__ eidx,
                            const unsigned short* __restrict__ xb,
                            unsigned short* __restrict__ meanb) {
    int t = threadIdx.x;
    int i = blockIdx.x * 8 + (t >> 5);
    int g = t & 31;
    if (i >= N_NODES) return;
    int beg = rowptr[i], end = rowptr[i + 1];
    float a0 = 0.f, a1 = 0.f, a2 = 0.f, a3 = 0.f;
    int j = beg;
    for (; j + 3 < end; j += 4) {
        int s0 = eidx[j], s1 = eidx[j + 1], s2 = eidx[j + 2], s3 = eidx[j + 3];
        ushort4 u0 = *(const ushort4*)&xb[(size_t)s0 * 128 + g * 4];
        ushort4 u1 = *(const ushort4*)&xb[(size_t)s1 * 128 + g * 4];
        ushort4 u2 = *(const ushort4*)&xb[(size_t)s2 * 128 + g * 4];
        ushort4 u3 = *(const ushort4*)&xb[(size_t)s3 * 128 + g * 4];
        a0 += bf2f(u0.x) + bf2f(u1.x) + bf2f(u2.x) + bf2f(u3.x);
        a1 += bf2f(u0.y) + bf2f(u1.y) + bf2f(u2.y) + bf2f(u3.y);
        a2 += bf2f(u0.z) + bf2f(u1.z) + bf2f(u2.z) + bf2f(u3.z);
        a3 += bf2f(u0.w) + bf2f(u1.w) + bf2f(u2.w) + bf2f(u3.w);
    }
    for (; j < end; ++j) {
        ushort4 u = *(const ushort4*)&xb[(size_t)eidx[j] * 128 + g * 4];
        a0 += bf2f(u.x); a1 += bf2f(u.y); a2 += bf2f(u.z); a3 += bf2f(u.w);
    }
    float inv = 1.0f / fmaxf((float)(end - beg), 1.0f);
    ushort4 r;
    r.x = f2bf(a0 * inv); r.y = f2bf(a1 * inv);
    r.z = f2bf(a2 * inv); r.w = f2bf(a3 * inv);
    *(ushort4*)&meanb[(size_t)i * 128 + g * 4] = r;
}

// out[i,o] = zr[i,o] + inv * sum_j zl[j,o]
__global__ void k_gather40(const int* __restrict__ rowptr, const int* __restrict__ eidx,
                           const unsigned short* __restrict__ zl,
                           const float* __restrict__ zr, float* __restrict__ out) {
    int t = threadIdx.x;
    int i = blockIdx.x * 8 + t / 40;
    int o = t % 40;
    int beg = rowptr[i], end = rowptr[i + 1];
    float acc = 0.0f;
    int j = beg;
    for (; j + 3 < end; j += 4) {
        int s0 = eidx[j], s1 = eidx[j + 1], s2 = eidx[j + 2], s3 = eidx[j + 3];
        acc += bf2f(zl[(size_t)s0 * 40 + o]) + bf2f(zl[(size_t)s1 * 40 + o])
             + bf2f(zl[(size_t)s2 * 40 + o]) + bf2f(zl[(size_t)s3 * 40 + o]);
    }
    for (; j < end; ++j)
        acc += bf2f(zl[(size_t)eidx[j] * 40 + o]);
    float inv = 1.0f / fmaxf((float)(end - beg), 1.0f);
    out[(size_t)i * 40 + o] = zr[(size_t)i * 40 + o] + acc * inv;
}

// ---------------- layer 1 dense (MFMA bf16) ----------------
__launch_bounds__(64)
__global__ void k_dense1_mfma(const unsigned short* __restrict__ meanb,
                              const unsigned short* __restrict__ xb,
                              const unsigned short* __restrict__ Bpk,
                              const float* __restrict__ b1,
                              unsigned short* __restrict__ hb) {
    int l  = threadIdx.x;          // 0..63
    int mt = blockIdx.x;           // 0..3124
    int m0 = mt * 16;
    int row = l & 15, kg = l >> 4;

    const unsigned short* mp = meanb + (size_t)(m0 + row) * 128 + kg * 8;
    const unsigned short* xp = xb    + (size_t)(m0 + row) * 128 + kg * 8;

    bf16x8 af[8];
#pragma unroll
    for (int kt = 0; kt < 4; ++kt) af[kt]     = *(const bf16x8*)(mp + kt * 32);
#pragma unroll
    for (int kt = 0; kt < 4; ++kt) af[4 + kt] = *(const bf16x8*)(xp + kt * 32);

    int rbase = m0 + (l >> 4) * 4;

#pragma unroll
    for (int ct = 0; ct < 8; ++ct) {
        f32x4 acc = {0.f, 0.f, 0.f, 0.f};
#pragma unroll
        for (int kt = 0; kt < 8; ++kt)
            acc = __builtin_amdgcn_mfma_f32_16x16x32_bf16(
                      af[kt],
                      *(const bf16x8*)(Bpk + (size_t)((kt * 8 + ct) * 64 + l) * 8),
                      acc, 0, 0, 0);
        int c = ct * 16 + (l & 15);
        float bias = b1[c];
#pragma unroll
        for (int r = 0; r < 4; ++r) {
            float v = fmaxf(acc[r] + bias, 0.0f);
            hb[(size_t)(rbase + r) * 128 + c] = f2bf(v);
        }
    }
}

// ---------------- layer 2 dense (MFMA bf16) ----------------
__launch_bounds__(64)
__global__ void k_dense2_mfma(const unsigned short* __restrict__ hb,
                              const unsigned short* __restrict__ Bpk,
                              const float* __restrict__ b2,
                              unsigned short* __restrict__ zl,
                              float* __restrict__ zr) {
    int l  = threadIdx.x;
    int mt = blockIdx.x;
    int m0 = mt * 16;
    int row = l & 15, kg = l >> 4;

    const unsigned short* hp = hb + (size_t)(m0 + row) * 128 + kg * 8;

    bf16x8 af[4];
#pragma unroll
    for (int kt = 0; kt < 4; ++kt) af[kt] = *(const bf16x8*)(hp + kt * 32);

    int rbase = m0 + (l >> 4) * 4;

#pragma unroll
    for (int ct = 0; ct < 5; ++ct) {
        f32x4 acc = {0.f, 0.f, 0.f, 0.f};
#pragma unroll
        for (int kt = 0; kt < 4; ++kt)
            acc = __builtin_amdgcn_mfma_f32_16x16x32_bf16(
                      af[kt],
                      *(const bf16x8*)(Bpk + (size_t)((kt * 5 + ct) * 64 + l) * 8),
                      acc, 0, 0, 0);
        int c = ct * 16 + (l & 15);
        if (c < 40) {
#pragma unroll
            for (int r = 0; r < 4; ++r)
                zl[(size_t)(rbase + r) * 40 + c] = f2bf(acc[r]);
        } else {
            float bias = b2[c - 40];
#pragma unroll
            for (int r = 0; r < 4; ++r)
                zr[(size_t)(rbase + r) * 40 + (c - 40)] = acc[r] + bias;
        }
    }
}

// ---------------- launch ----------------

extern "C" void kernel_launch(void* const* d_in, const int* in_sizes, int n_in,
                              void* d_out, int out_size, void* d_ws, size_t ws_size,
                              hipStream_t stream) {
    const float* x   = (const float*)d_in[0];
    const int*   ei  = (const int*)d_in[1];      // [2, E] int32
    const float* W1l = (const float*)d_in[2];
    const float* b1  = (const float*)d_in[3];
    const float* W1r = (const float*)d_in[4];
    const float* W2l = (const float*)d_in[5];
    const float* b2  = (const float*)d_in[6];
    const float* W2r = (const float*)d_in[7];

    const int* src = ei;
    const int* dst = ei + E_EDGES;

    // ---- workspace carve (16B-aligned) ----
    char* base = (char*)d_ws;
    size_t off = 0;
    auto carve = [&](size_t bytes) {
        void* p = base + off;
        off += (bytes + 15) & ~(size_t)15;
        return p;
    };
    int*   cnt    = (int*)  carve((size_t)N_NODES * 4);
    int*   rowptr = (int*)  carve((size_t)(N_NODES + 1) * 4);
    int*   cursor = (int*)  carve((size_t)N_NODES * 4);
    int*   eidx   = (int*)  carve((size_t)E_EDGES * 4);
    int*   bsum   = (int*)  carve((size_t)256 * 4);
    int*   boff   = (int*)  carve((size_t)256 * 4);
    unsigned short* bpk1  = (unsigned short*)carve((size_t)8 * 8 * 64 * 8 * 2);   // 64 KB
    unsigned short* bpk2  = (unsigned short*)carve((size_t)4 * 5 * 64 * 8 * 2);   // 20 KB
    unsigned short* xb    = (unsigned short*)carve((size_t)N_NODES * 128 * 2);
    unsigned short* meanb = (unsigned short*)carve((size_t)N_NODES * 128 * 2);
    unsigned short* hb    = (unsigned short*)carve((size_t)N_NODES * 128 * 2);
    unsigned short* zl    = (unsigned short*)carve((size_t)N_NODES * 40 * 2);
    float*          zr    = (float*)carve((size_t)N_NODES * 40 * 4);
    float* outp = (float*)d_out;

    // ---- CSR build ----
    k_zero<<<SCAN_NBLK, 256, 0, stream>>>(cnt);
    k_count<<<(E_EDGES + 255) / 256, 256, 0, stream>>>(dst, cnt);
    k_scan_part<<<SCAN_NBLK, 256, 0, stream>>>(cnt, rowptr, bsum);
    k_scan_bsum<<<1, 256, 0, stream>>>(bsum, boff);
    k_scan_add<<<SCAN_NBLK, 256, 0, stream>>>(rowptr, boff, cursor);
    {
        int chunks = (E_EDGES + 255) / 256;           // 3125
        k_fill_shard<<<chunks * NSHARD, 256, 0, stream>>>(src, dst, cursor, eidx);
    }

    // ---- casts + weight packing ----
    k_cast<<<2048, 256, 0, stream>>>(x, xb);
    k_pack<<<(8 * 8 * 64 + 4 * 5 * 64 + 255) / 256, 256, 0, stream>>>(
        W1l, W1r, W2l, W2r, bpk1, bpk2);

    // ---- layer 1 ----
    k_gather128<<<(N_NODES + 7) / 8, 256, 0, stream>>>(rowptr, eidx, xb, meanb);
    k_dense1_mfma<<<N_NODES / 16, 64, 0, stream>>>(meanb, xb, bpk1, b1, hb);

    // ---- layer 2 ----
    k_dense2_mfma<<<N_NODES / 16, 64, 0, stream>>>(hb, bpk2, b2, zl, zr);
    k_gather40<<<(N_NODES + 7) / 8, 320, 0, stream>>>(rowptr, eidx, zl, zr, outp);
}

// Round 15
// 169.935 us; speedup vs baseline: 1.6227x; 1.0954x over previous
//
#include <hip/hip_runtime.h>

#define N_NODES 50000
#define E_EDGES 800000
#define SCAN_NBLK 196   // ceil(50000/256)
#define NSHARD 8
#define SHARD_W (N_NODES / NSHARD)   // 6250

typedef __attribute__((ext_vector_type(8))) short bf16x8;
typedef __attribute__((ext_vector_type(4))) float f32x4;

__device__ __forceinline__ unsigned short f2bf(float f) {
    unsigned u = __float_as_uint(f);
    u = (u + 0x7FFF + ((u >> 16) & 1)) >> 16;   // RNE
    return (unsigned short)u;
}
__device__ __forceinline__ float bf2f(unsigned short s) {
    return __uint_as_float(((unsigned)s) << 16);
}

// XOR-swizzled LDS addressing for [16][128]-bf16 tiles (256 B/row):
// byte ^= (row&7)<<4 spreads the 256B-strided column reads across 8 bank
// groups (16-way conflict -> 2-way = free, per guide §6 G4).
__device__ __forceinline__ unsigned short* lds_ptr(unsigned short* base, int row,
                                                   int byte_in_row) {
    return (unsigned short*)((char*)base + row * 256 + (byte_in_row ^ ((row & 7) << 4)));
}

// ---------------- CSR build ----------------

__global__ void k_count(const int* __restrict__ dst, int* __restrict__ cnt) {
    int e = blockIdx.x * blockDim.x + threadIdx.x;
    if (e < E_EDGES) atomicAdd(&cnt[dst[e]], 1);
}

__global__ void k_scan_part(const int* __restrict__ cnt, int* __restrict__ excl,
                            int* __restrict__ bsum) {
    __shared__ int sm[256];
    int b = blockIdx.x, t = threadIdx.x;
    int i = b * 256 + t;
    int v = (i < N_NODES) ? cnt[i] : 0;
    sm[t] = v;
    __syncthreads();
    for (int off = 1; off < 256; off <<= 1) {
        int u = (t >= off) ? sm[t - off] : 0;
        __syncthreads();
        sm[t] += u;
        __syncthreads();
    }
    if (i < N_NODES) excl[i] = sm[t] - v;
    if (t == 255) bsum[b] = sm[255];
}

// fused bsum-scan + offset-add: every block redundantly scans the 196 block
// sums (trivial) -> saves the separate single-block k_scan_bsum launch.
__global__ void k_scan_add2(int* __restrict__ rowptr, const int* __restrict__ bsum,
                            int* __restrict__ cursor) {
    __shared__ int sm[256];
    int b = blockIdx.x, t = threadIdx.x;
    int v = (t < SCAN_NBLK) ? bsum[t] : 0;
    sm[t] = v;
    __syncthreads();
    for (int off = 1; off < 256; off <<= 1) {
        int u = (t >= off) ? sm[t - off] : 0;
        __syncthreads();
        sm[t] += u;
        __syncthreads();
    }
    int boff = (b == 0) ? 0 : sm[b - 1];
    int i = b * 256 + t;
    if (i < N_NODES) {
        int r = rowptr[i] + boff;
        rowptr[i] = r;
        cursor[i] = r;
    }
    if (b == 0 && t == 0) rowptr[N_NODES] = E_EDGES;
}

// dst-range-sharded fill (shard = blockIdx&7 -> XCD round-robin): all writes
// to a given eidx line assemble within one XCD's L2 -> ~full-line writeback.
__global__ void k_fill_shard(const int* __restrict__ src, const int* __restrict__ dst,
                             int* __restrict__ cursor, int* __restrict__ eidx) {
    int shard = blockIdx.x & (NSHARD - 1);
    int chunk = blockIdx.x >> 3;
    int e = chunk * 256 + threadIdx.x;
    if (e >= E_EDGES) return;
    int d = dst[e];
    int lo = shard * SHARD_W;
    if (d >= lo && d < lo + SHARD_W) {
        int p = atomicAdd(&cursor[d], 1);
        eidx[p] = src[e];
    }
}

// ---------------- fused preprocessing: cast + cnt-zero + weight pack ----------------
// grid = 6250 blocks x 256 thr. Every thread casts one float4 group of x;
// blocks <196 also zero cnt; blocks [196,217) also pack B1/B2 fragments.
__global__ void k_pre(const float* __restrict__ x, unsigned short* __restrict__ xb,
                      int* __restrict__ cnt,
                      const float* __restrict__ W1l, const float* __restrict__ W1r,
                      const float* __restrict__ W2l, const float* __restrict__ W2r,
                      unsigned short* __restrict__ Bpk1,
                      unsigned short* __restrict__ Bpk2) {
    int b = blockIdx.x, t = threadIdx.x;
    int i4 = b * 256 + t;          // exactly N_NODES*32 = 1.6M groups
    {
        float4 v = ((const float4*)x)[i4];
        ushort4 o;
        o.x = f2bf(v.x); o.y = f2bf(v.y); o.z = f2bf(v.z); o.w = f2bf(v.w);
        ((ushort4*)xb)[i4] = o;
    }
    if (b < SCAN_NBLK) {
        int i = b * 256 + t;
        if (i < N_NODES) cnt[i] = 0;
    } else if (b < SCAN_NBLK + 21) {
        int idx = (b - SCAN_NBLK) * 256 + t;
        if (idx < 8 * 8 * 64) {
            int kt = idx >> 9, ct = (idx >> 6) & 7, l = idx & 63;
            int c  = ct * 16 + (l & 15);
            int k0 = kt * 32 + (l >> 4) * 8;
            const float* Wr = (k0 < 128) ? (W1l + (size_t)c * 128 + k0)
                                         : (W1r + (size_t)c * 128 + (k0 - 128));
            bf16x8 v;
#pragma unroll
            for (int i = 0; i < 8; ++i) v[i] = (short)f2bf(Wr[i]);
            *(bf16x8*)(Bpk1 + (size_t)idx * 8) = v;
        } else if (idx < 8 * 8 * 64 + 4 * 5 * 64) {
            int j = idx - 8 * 8 * 64;
            int kt = j / 320, rem = j - kt * 320;
            int ct = rem >> 6, l = rem & 63;
            int c  = ct * 16 + (l & 15);
            int k0 = kt * 32 + (l >> 4) * 8;
            const float* Wr = (c < 40) ? (W2l + (size_t)c * 128 + k0)
                                       : (W2r + (size_t)(c - 40) * 128 + k0);
            bf16x8 v;
#pragma unroll
            for (int i = 0; i < 8; ++i) v[i] = (short)f2bf(Wr[i]);
            *(bf16x8*)(Bpk2 + (size_t)j * 8) = v;
        }
    }
}

// ---------------- fused gather128 + dense1 + dense2 ----------------
// One block = 16-node tile, 256 thr = 4 waves.
// P1: gather mean (16 lanes/node, bf16x8 loads, fp32 acc) -> swizzled LDS.
// P2: dense1 MFMA, 2 c-tiles/wave, h -> swizzled LDS (relu+bias applied).
// P3: dense2 MFMA, c-tiles {wv} + wv0 takes ct4; zl (bf16) / zr (f32+bias) out.
__launch_bounds__(256)
__global__ void k_fused(const int* __restrict__ rowptr, const int* __restrict__ eidx,
                        const unsigned short* __restrict__ xb,
                        const unsigned short* __restrict__ Bpk1,
                        const unsigned short* __restrict__ Bpk2,
                        const float* __restrict__ b1, const float* __restrict__ b2,
                        unsigned short* __restrict__ zl, float* __restrict__ zr) {
    __shared__ unsigned short meanS[16 * 128];
    __shared__ unsigned short hS[16 * 128];
    int t = threadIdx.x;
    int m0 = blockIdx.x * 16;

    // ---- P1: gather ----
    {
        int nl = t >> 4;              // node local 0..15
        int f0 = (t & 15) * 8;        // feature start
        int i = m0 + nl;
        int beg = rowptr[i], end = rowptr[i + 1];
        float a[8] = {0, 0, 0, 0, 0, 0, 0, 0};
        int j = beg;
        for (; j + 3 < end; j += 4) {
            int s0 = eidx[j], s1 = eidx[j + 1], s2 = eidx[j + 2], s3 = eidx[j + 3];
            bf16x8 u0 = *(const bf16x8*)(xb + (size_t)s0 * 128 + f0);
            bf16x8 u1 = *(const bf16x8*)(xb + (size_t)s1 * 128 + f0);
            bf16x8 u2 = *(const bf16x8*)(xb + (size_t)s2 * 128 + f0);
            bf16x8 u3 = *(const bf16x8*)(xb + (size_t)s3 * 128 + f0);
#pragma unroll
            for (int q = 0; q < 8; ++q)
                a[q] += bf2f((unsigned short)u0[q]) + bf2f((unsigned short)u1[q])
                      + bf2f((unsigned short)u2[q]) + bf2f((unsigned short)u3[q]);
        }
        for (; j < end; ++j) {
            bf16x8 u = *(const bf16x8*)(xb + (size_t)eidx[j] * 128 + f0);
#pragma unroll
            for (int q = 0; q < 8; ++q) a[q] += bf2f((unsigned short)u[q]);
        }
        float inv = 1.0f / fmaxf((float)(end - beg), 1.0f);
        bf16x8 r;
#pragma unroll
        for (int q = 0; q < 8; ++q) r[q] = (short)f2bf(a[q] * inv);
        *(bf16x8*)lds_ptr(meanS, nl, f0 * 2) = r;
    }
    __syncthreads();

    // ---- P2: dense1 ----
    int l = t & 63, wv = t >> 6;
    int row = l & 15, kg = l >> 4;

    bf16x8 af[8];
#pragma unroll
    for (int kt = 0; kt < 4; ++kt)
        af[kt] = *(const bf16x8*)lds_ptr(meanS, row, kg * 16 + kt * 64);
    {
        const unsigned short* xp = xb + (size_t)(m0 + row) * 128 + kg * 8;
#pragma unroll
        for (int kt = 0; kt < 4; ++kt)
            af[4 + kt] = *(const bf16x8*)(xp + kt * 32);
    }

#pragma unroll
    for (int cc = 0; cc < 2; ++cc) {
        int ct = wv * 2 + cc;
        f32x4 acc = {0.f, 0.f, 0.f, 0.f};
#pragma unroll
        for (int kt = 0; kt < 8; ++kt)
            acc = __builtin_amdgcn_mfma_f32_16x16x32_bf16(
                      af[kt],
                      *(const bf16x8*)(Bpk1 + (size_t)((kt * 8 + ct) * 64 + l) * 8),
                      acc, 0, 0, 0);
        int c = ct * 16 + (l & 15);
        float bias = b1[c];
#pragma unroll
        for (int r4 = 0; r4 < 4; ++r4) {
            float v = fmaxf(acc[r4] + bias, 0.0f);
            *lds_ptr(hS, kg * 4 + r4, c * 2) = f2bf(v);
        }
    }
    __syncthreads();

    // ---- P3: dense2 ----
    bf16x8 hf[4];
#pragma unroll
    for (int kt = 0; kt < 4; ++kt)
        hf[kt] = *(const bf16x8*)lds_ptr(hS, row, kg * 16 + kt * 64);

    int rbase = m0 + kg * 4;
    int nct = (wv == 0) ? 2 : 1;
    for (int q = 0; q < nct; ++q) {
        int ct = (q == 0) ? wv : 4;
        f32x4 acc = {0.f, 0.f, 0.f, 0.f};
#pragma unroll
        for (int kt = 0; kt < 4; ++kt)
            acc = __builtin_amdgcn_mfma_f32_16x16x32_bf16(
                      hf[kt],
                      *(const bf16x8*)(Bpk2 + (size_t)((kt * 5 + ct) * 64 + l) * 8),
                      acc, 0, 0, 0);
        int c = ct * 16 + (l & 15);
        if (c < 40) {
#pragma unroll
            for (int r4 = 0; r4 < 4; ++r4)
                zl[(size_t)(rbase + r4) * 40 + c] = f2bf(acc[r4]);
        } else {
            float bias = b2[c - 40];
#pragma unroll
            for (int r4 = 0; r4 < 4; ++r4)
                zr[(size_t)(rbase + r4) * 40 + (c - 40)] = acc[r4] + bias;
        }
    }
}

// ---------------- layer-2 gather ----------------
// out[i,o] = zr[i,o] + inv * sum_j zl[j,o]
__global__ void k_gather40(const int* __restrict__ rowptr, const int* __restrict__ eidx,
                           const unsigned short* __restrict__ zl,
                           const float* __restrict__ zr, float* __restrict__ out) {
    int t = threadIdx.x;
    int i = blockIdx.x * 8 + t / 40;
    int o = t % 40;
    int beg = rowptr[i], end = rowptr[i + 1];
    float acc = 0.0f;
    int j = beg;
    for (; j + 3 < end; j += 4) {
        int s0 = eidx[j], s1 = eidx[j + 1], s2 = eidx[j + 2], s3 = eidx[j + 3];
        acc += bf2f(zl[(size_t)s0 * 40 + o]) + bf2f(zl[(size_t)s1 * 40 + o])
             + bf2f(zl[(size_t)s2 * 40 + o]) + bf2f(zl[(size_t)s3 * 40 + o]);
    }
    for (; j < end; ++j)
        acc += bf2f(zl[(size_t)eidx[j] * 40 + o]);
    float inv = 1.0f / fmaxf((float)(end - beg), 1.0f);
    out[(size_t)i * 40 + o] = zr[(size_t)i * 40 + o] + acc * inv;
}

// ---------------- launch ----------------

extern "C" void kernel_launch(void* const* d_in, const int* in_sizes, int n_in,
                              void* d_out, int out_size, void* d_ws, size_t ws_size,
                              hipStream_t stream) {
    const float* x   = (const float*)d_in[0];
    const int*   ei  = (const int*)d_in[1];      // [2, E] int32
    const float* W1l = (const float*)d_in[2];
    const float* b1  = (const float*)d_in[3];
    const float* W1r = (const float*)d_in[4];
    const float* W2l = (const float*)d_in[5];
    const float* b2  = (const float*)d_in[6];
    const float* W2r = (const float*)d_in[7];

    const int* src = ei;
    const int* dst = ei + E_EDGES;

    // ---- workspace carve (16B-aligned) ----
    char* base = (char*)d_ws;
    size_t off = 0;
    auto carve = [&](size_t bytes) {
        void* p = base + off;
        off += (bytes + 15) & ~(size_t)15;
        return p;
    };
    int*   cnt    = (int*)  carve((size_t)N_NODES * 4);
    int*   rowptr = (int*)  carve((size_t)(N_NODES + 1) * 4);
    int*   cursor = (int*)  carve((size_t)N_NODES * 4);
    int*   eidx   = (int*)  carve((size_t)E_EDGES * 4);
    int*   bsum   = (int*)  carve((size_t)256 * 4);
    unsigned short* bpk1 = (unsigned short*)carve((size_t)8 * 8 * 64 * 8 * 2);  // 64 KB
    unsigned short* bpk2 = (unsigned short*)carve((size_t)4 * 5 * 64 * 8 * 2);  // 20 KB
    unsigned short* xb   = (unsigned short*)carve((size_t)N_NODES * 128 * 2);
    unsigned short* zl   = (unsigned short*)carve((size_t)N_NODES * 40 * 2);
    float*          zr   = (float*)carve((size_t)N_NODES * 40 * 4);
    float* outp = (float*)d_out;

    // ---- preprocessing (cast + zero + pack) ----
    k_pre<<<N_NODES * 32 / 256, 256, 0, stream>>>(x, xb, cnt, W1l, W1r, W2l, W2r,
                                                  bpk1, bpk2);

    // ---- CSR build ----
    k_count<<<(E_EDGES + 255) / 256, 256, 0, stream>>>(dst, cnt);
    k_scan_part<<<SCAN_NBLK, 256, 0, stream>>>(cnt, rowptr, bsum);
    k_scan_add2<<<SCAN_NBLK, 256, 0, stream>>>(rowptr, bsum, cursor);
    {
        int chunks = (E_EDGES + 255) / 256;           // 3125
        k_fill_shard<<<chunks * NSHARD, 256, 0, stream>>>(src, dst, cursor, eidx);
    }

    // ---- fused gather + dense1 + dense2 ----
    k_fused<<<N_NODES / 16, 256, 0, stream>>>(rowptr, eidx, xb, bpk1, bpk2,
                                              b1, b2, zl, zr);

    // ---- layer-2 gather ----
    k_gather40<<<(N_NODES + 7) / 8, 320, 0, stream>>>(rowptr, eidx, zl, zr, outp);
}

// Round 16
// 157.493 us; speedup vs baseline: 1.7509x; 1.0790x over previous
//
#include <hip/hip_runtime.h>

#define N_NODES 50000
#define E_EDGES 800000
#define SCAN_NBLK 196   // ceil(50000/256)
#define NSHARD 8
#define SHARD_W (N_NODES / NSHARD)   // 6250

typedef __attribute__((ext_vector_type(8))) short bf16x8;
typedef __attribute__((ext_vector_type(4))) float f32x4;

__device__ __forceinline__ unsigned short f2bf(float f) {
    unsigned u = __float_as_uint(f);
    u = (u + 0x7FFF + ((u >> 16) & 1)) >> 16;   // RNE
    return (unsigned short)u;
}
__device__ __forceinline__ float bf2f(unsigned short s) {
    return __uint_as_float(((unsigned)s) << 16);
}

// XOR-swizzled LDS addressing for [16][128]-bf16 tiles (256 B/row):
// byte ^= (row&7)<<4 spreads 256B-strided column reads across 8 bank groups.
__device__ __forceinline__ unsigned short* lds_ptr(unsigned short* base, int row,
                                                   int byte_in_row) {
    return (unsigned short*)((char*)base + row * 256 + (byte_in_row ^ ((row & 7) << 4)));
}

// ---------------- CSR build ----------------

// our own zero (rocclr fillBuffer measured 42us for this size)
__global__ void k_zero(int* __restrict__ cnt) {
    int i = blockIdx.x * blockDim.x + threadIdx.x;
    if (i < N_NODES) cnt[i] = 0;
}

__global__ void k_scan_part(const int* __restrict__ cnt, int* __restrict__ excl,
                            int* __restrict__ bsum) {
    __shared__ int sm[256];
    int b = blockIdx.x, t = threadIdx.x;
    int i = b * 256 + t;
    int v = (i < N_NODES) ? cnt[i] : 0;
    sm[t] = v;
    __syncthreads();
    for (int off = 1; off < 256; off <<= 1) {
        int u = (t >= off) ? sm[t - off] : 0;
        __syncthreads();
        sm[t] += u;
        __syncthreads();
    }
    if (i < N_NODES) excl[i] = sm[t] - v;
    if (t == 255) bsum[b] = sm[255];
}

// fused bsum-scan + offset-add (each block redundantly scans the 196 sums)
__global__ void k_scan_add2(int* __restrict__ rowptr, const int* __restrict__ bsum,
                            int* __restrict__ cursor) {
    __shared__ int sm[256];
    int b = blockIdx.x, t = threadIdx.x;
    int v = (t < SCAN_NBLK) ? bsum[t] : 0;
    sm[t] = v;
    __syncthreads();
    for (int off = 1; off < 256; off <<= 1) {
        int u = (t >= off) ? sm[t - off] : 0;
        __syncthreads();
        sm[t] += u;
        __syncthreads();
    }
    int boff = (b == 0) ? 0 : sm[b - 1];
    int i = b * 256 + t;
    if (i < N_NODES) {
        int r = rowptr[i] + boff;
        rowptr[i] = r;
        cursor[i] = r;
    }
    if (b == 0 && t == 0) rowptr[N_NODES] = E_EDGES;
}

// dst-range-sharded fill (shard = blockIdx&7 -> XCD round-robin): writes to a
// given eidx line assemble within one XCD's L2 -> ~full-line writeback.
__global__ void k_fill_shard(const int* __restrict__ src, const int* __restrict__ dst,
                             int* __restrict__ cursor, int* __restrict__ eidx) {
    int shard = blockIdx.x & (NSHARD - 1);
    int chunk = blockIdx.x >> 3;
    int e = chunk * 256 + threadIdx.x;
    if (e >= E_EDGES) return;
    int d = dst[e];
    int lo = shard * SHARD_W;
    if (d >= lo && d < lo + SHARD_W) {
        int p = atomicAdd(&cursor[d], 1);
        eidx[p] = src[e];
    }
}

// ---------------- fused preprocessing: cast + degree-count + weight pack ----
// 6250 blocks x 256 thr. Every thread casts one float4 group of x; threads
// t<128 also count one edge (b*128+t covers E exactly); blocks <21 also pack
// B1/B2 MFMA fragments (21*256 = 5376 = 4096+1280 exactly).
__global__ void k_pre(const float* __restrict__ x, unsigned short* __restrict__ xb,
                      const int* __restrict__ dst, int* __restrict__ cnt,
                      const float* __restrict__ W1l, const float* __restrict__ W1r,
                      const float* __restrict__ W2l, const float* __restrict__ W2r,
                      unsigned short* __restrict__ Bpk1,
                      unsigned short* __restrict__ Bpk2) {
    int b = blockIdx.x, t = threadIdx.x;
    int i4 = b * 256 + t;          // exactly N_NODES*32 = 1.6M groups
    {
        float4 v = ((const float4*)x)[i4];
        ushort4 o;
        o.x = f2bf(v.x); o.y = f2bf(v.y); o.z = f2bf(v.z); o.w = f2bf(v.w);
        ((ushort4*)xb)[i4] = o;
    }
    if (t < 128) {
        int e = b * 128 + t;       // 6250*128 = 800000 exactly
        atomicAdd(&cnt[dst[e]], 1);
    }
    if (b < 21) {
        int idx = b * 256 + t;
        if (idx < 8 * 8 * 64) {
            int kt = idx >> 9, ct = (idx >> 6) & 7, l = idx & 63;
            int c  = ct * 16 + (l & 15);
            int k0 = kt * 32 + (l >> 4) * 8;
            const float* Wr = (k0 < 128) ? (W1l + (size_t)c * 128 + k0)
                                         : (W1r + (size_t)c * 128 + (k0 - 128));
            bf16x8 v;
#pragma unroll
            for (int i = 0; i < 8; ++i) v[i] = (short)f2bf(Wr[i]);
            *(bf16x8*)(Bpk1 + (size_t)idx * 8) = v;
        } else {
            int j = idx - 8 * 8 * 64;   // < 1280
            int kt = j / 320, rem = j - kt * 320;
            int ct = rem >> 6, l = rem & 63;
            int c  = ct * 16 + (l & 15);
            int k0 = kt * 32 + (l >> 4) * 8;
            const float* Wr = (c < 40) ? (W2l + (size_t)c * 128 + k0)
                                       : (W2r + (size_t)(c - 40) * 128 + k0);
            bf16x8 v;
#pragma unroll
            for (int i = 0; i < 8; ++i) v[i] = (short)f2bf(Wr[i]);
            *(bf16x8*)(Bpk2 + (size_t)j * 8) = v;
        }
    }
}

// ---------------- fused gather128 + dense1 + dense2 ----------------
// One block = 16-node tile, 256 thr = 4 waves.
// P1: split-K gather: 2 edge-groups x 16 nodes x 8 lanes (2 bf16x8 each);
//     group partials combined via bf16 staging in hS (dead until P2).
// P2: dense1 MFMA, 2 c-tiles/wave, h -> swizzled hS.
// P3: dense2 MFMA; zl (bf16) / zr (f32+bias) out.
__launch_bounds__(256)
__global__ void k_fused(const int* __restrict__ rowptr, const int* __restrict__ eidx,
                        const unsigned short* __restrict__ xb,
                        const unsigned short* __restrict__ Bpk1,
                        const unsigned short* __restrict__ Bpk2,
                        const float* __restrict__ b1, const float* __restrict__ b2,
                        unsigned short* __restrict__ zl, float* __restrict__ zr) {
    __shared__ unsigned short meanS[16 * 128];
    __shared__ unsigned short hS[16 * 128];     // doubles as partial-sum staging in P1
    int t = threadIdx.x;
    int m0 = blockIdx.x * 16;

    // ---- P1: split-K gather ----
    {
        int eg = t >> 7;              // edge group 0/1
        int rem = t & 127;
        int nl = rem >> 3;            // node local 0..15
        int ln = rem & 7;             // feature lane 0..7
        int fb = ln * 32;             // byte offset of 32B feature span (16 feats)
        int i = m0 + nl;
        int beg = rowptr[i], end = rowptr[i + 1];
        float a[16];
#pragma unroll
        for (int q = 0; q < 16; ++q) a[q] = 0.0f;
        int j = beg + eg;
        for (; j + 2 < end; j += 4) {
            const unsigned short* r0 = xb + (size_t)eidx[j] * 128 + ln * 16;
            const unsigned short* r1 = xb + (size_t)eidx[j + 2] * 128 + ln * 16;
            bf16x8 u0 = *(const bf16x8*)(r0);
            bf16x8 u1 = *(const bf16x8*)(r0 + 8);
            bf16x8 u2 = *(const bf16x8*)(r1);
            bf16x8 u3 = *(const bf16x8*)(r1 + 8);
#pragma unroll
            for (int q = 0; q < 8; ++q) {
                a[q]     += bf2f((unsigned short)u0[q]) + bf2f((unsigned short)u2[q]);
                a[8 + q] += bf2f((unsigned short)u1[q]) + bf2f((unsigned short)u3[q]);
            }
        }
        if (j < end) {
            const unsigned short* r0 = xb + (size_t)eidx[j] * 128 + ln * 16;
            bf16x8 u0 = *(const bf16x8*)(r0);
            bf16x8 u1 = *(const bf16x8*)(r0 + 8);
#pragma unroll
            for (int q = 0; q < 8; ++q) {
                a[q]     += bf2f((unsigned short)u0[q]);
                a[8 + q] += bf2f((unsigned short)u1[q]);
            }
        }
        if (eg == 0) {                 // stage group-0 partials (bf16) in hS
            bf16x8 p0, p1;
#pragma unroll
            for (int q = 0; q < 8; ++q) {
                p0[q] = (short)f2bf(a[q]);
                p1[q] = (short)f2bf(a[8 + q]);
            }
            *(bf16x8*)lds_ptr(hS, nl, fb)      = p0;
            *(bf16x8*)lds_ptr(hS, nl, fb + 16) = p1;
        }
        __syncthreads();
        if (eg == 1) {                 // combine + scale + write mean
            bf16x8 p0 = *(const bf16x8*)lds_ptr(hS, nl, fb);
            bf16x8 p1 = *(const bf16x8*)lds_ptr(hS, nl, fb + 16);
            float inv = 1.0f / fmaxf((float)(end - beg), 1.0f);
            bf16x8 r0, r1;
#pragma unroll
            for (int q = 0; q < 8; ++q) {
                r0[q] = (short)f2bf((a[q] + bf2f((unsigned short)p0[q])) * inv);
                r1[q] = (short)f2bf((a[8 + q] + bf2f((unsigned short)p1[q])) * inv);
            }
            *(bf16x8*)lds_ptr(meanS, nl, fb)      = r0;
            *(bf16x8*)lds_ptr(meanS, nl, fb + 16) = r1;
        }
    }
    __syncthreads();

    // ---- P2: dense1 ----
    int l = t & 63, wv = t >> 6;
    int row = l & 15, kg = l >> 4;

    bf16x8 af[8];
#pragma unroll
    for (int kt = 0; kt < 4; ++kt)
        af[kt] = *(const bf16x8*)lds_ptr(meanS, row, kg * 16 + kt * 64);
    {
        const unsigned short* xp = xb + (size_t)(m0 + row) * 128 + kg * 8;
#pragma unroll
        for (int kt = 0; kt < 4; ++kt)
            af[4 + kt] = *(const bf16x8*)(xp + kt * 32);
    }
    __syncthreads();    // hS partials fully consumed before overwrite

#pragma unroll
    for (int cc = 0; cc < 2; ++cc) {
        int ct = wv * 2 + cc;
        f32x4 acc = {0.f, 0.f, 0.f, 0.f};
#pragma unroll
        for (int kt = 0; kt < 8; ++kt)
            acc = __builtin_amdgcn_mfma_f32_16x16x32_bf16(
                      af[kt],
                      *(const bf16x8*)(Bpk1 + (size_t)((kt * 8 + ct) * 64 + l) * 8),
                      acc, 0, 0, 0);
        int c = ct * 16 + (l & 15);
        float bias = b1[c];
#pragma unroll
        for (int r4 = 0; r4 < 4; ++r4) {
            float v = fmaxf(acc[r4] + bias, 0.0f);
            *lds_ptr(hS, kg * 4 + r4, c * 2) = f2bf(v);
        }
    }
    __syncthreads();

    // ---- P3: dense2 ----
    bf16x8 hf[4];
#pragma unroll
    for (int kt = 0; kt < 4; ++kt)
        hf[kt] = *(const bf16x8*)lds_ptr(hS, row, kg * 16 + kt * 64);

    int rbase = m0 + kg * 4;
    int nct = (wv == 0) ? 2 : 1;
    for (int q = 0; q < nct; ++q) {
        int ct = (q == 0) ? wv : 4;
        f32x4 acc = {0.f, 0.f, 0.f, 0.f};
#pragma unroll
        for (int kt = 0; kt < 4; ++kt)
            acc = __builtin_amdgcn_mfma_f32_16x16x32_bf16(
                      hf[kt],
                      *(const bf16x8*)(Bpk2 + (size_t)((kt * 5 + ct) * 64 + l) * 8),
                      acc, 0, 0, 0);
        int c = ct * 16 + (l & 15);
        if (c < 40) {
#pragma unroll
            for (int r4 = 0; r4 < 4; ++r4)
                zl[(size_t)(rbase + r4) * 40 + c] = f2bf(acc[r4]);
        } else {
            float bias = b2[c - 40];
#pragma unroll
            for (int r4 = 0; r4 < 4; ++r4)
                zr[(size_t)(rbase + r4) * 40 + (c - 40)] = acc[r4] + bias;
        }
    }
}

// ---------------- layer-2 gather ----------------
// out[i,:] = zr[i,:] + inv * sum_j zl[j,:]
// block = 320 thr = 64 nodes x 5 lanes; lane owns one bf16x8 chunk (40 = 5*8).
__global__ void k_gather40(const int* __restrict__ rowptr, const int* __restrict__ eidx,
                           const unsigned short* __restrict__ zl,
                           const float* __restrict__ zr, float* __restrict__ out) {
    int t = threadIdx.x;
    int nl = t / 5, ln = t - nl * 5;
    int i = blockIdx.x * 64 + nl;
    if (i >= N_NODES) return;
    int beg = rowptr[i], end = rowptr[i + 1];
    float a[8];
#pragma unroll
    for (int q = 0; q < 8; ++q) a[q] = 0.0f;
    int j = beg;
    for (; j + 1 < end; j += 2) {
        bf16x8 u0 = *(const bf16x8*)(zl + (size_t)eidx[j] * 40 + ln * 8);
        bf16x8 u1 = *(const bf16x8*)(zl + (size_t)eidx[j + 1] * 40 + ln * 8);
#pragma unroll
        for (int q = 0; q < 8; ++q)
            a[q] += bf2f((unsigned short)u0[q]) + bf2f((unsigned short)u1[q]);
    }
    if (j < end) {
        bf16x8 u = *(const bf16x8*)(zl + (size_t)eidx[j] * 40 + ln * 8);
#pragma unroll
        for (int q = 0; q < 8; ++q) a[q] += bf2f((unsigned short)u[q]);
    }
    float inv = 1.0f / fmaxf((float)(end - beg), 1.0f);
    size_t base = (size_t)i * 40 + ln * 8;
    float4 z0 = *(const float4*)(zr + base);
    float4 z1 = *(const float4*)(zr + base + 4);
    float4 o0, o1;
    o0.x = z0.x + a[0] * inv; o0.y = z0.y + a[1] * inv;
    o0.z = z0.z + a[2] * inv; o0.w = z0.w + a[3] * inv;
    o1.x = z1.x + a[4] * inv; o1.y = z1.y + a[5] * inv;
    o1.z = z1.z + a[6] * inv; o1.w = z1.w + a[7] * inv;
    *(float4*)(out + base) = o0;
    *(float4*)(out + base + 4) = o1;
}

// ---------------- launch ----------------

extern "C" void kernel_launch(void* const* d_in, const int* in_sizes, int n_in,
                              void* d_out, int out_size, void* d_ws, size_t ws_size,
                              hipStream_t stream) {
    const float* x   = (const float*)d_in[0];
    const int*   ei  = (const int*)d_in[1];      // [2, E] int32
    const float* W1l = (const float*)d_in[2];
    const float* b1  = (const float*)d_in[3];
    const float* W1r = (const float*)d_in[4];
    const float* W2l = (const float*)d_in[5];
    const float* b2  = (const float*)d_in[6];
    const float* W2r = (const float*)d_in[7];

    const int* src = ei;
    const int* dst = ei + E_EDGES;

    // ---- workspace carve (16B-aligned) ----
    char* base = (char*)d_ws;
    size_t off = 0;
    auto carve = [&](size_t bytes) {
        void* p = base + off;
        off += (bytes + 15) & ~(size_t)15;
        return p;
    };
    int*   cnt    = (int*)  carve((size_t)N_NODES * 4);
    int*   rowptr = (int*)  carve((size_t)(N_NODES + 1) * 4);
    int*   cursor = (int*)  carve((size_t)N_NODES * 4);
    int*   eidx   = (int*)  carve((size_t)E_EDGES * 4);
    int*   bsum   = (int*)  carve((size_t)256 * 4);
    unsigned short* bpk1 = (unsigned short*)carve((size_t)8 * 8 * 64 * 8 * 2);  // 64 KB
    unsigned short* bpk2 = (unsigned short*)carve((size_t)4 * 5 * 64 * 8 * 2);  // 20 KB
    unsigned short* xb   = (unsigned short*)carve((size_t)N_NODES * 128 * 2);
    unsigned short* zl   = (unsigned short*)carve((size_t)N_NODES * 40 * 2);
    float*          zr   = (float*)carve((size_t)N_NODES * 40 * 4);
    float* outp = (float*)d_out;

    // ---- CSR build + preprocessing ----
    k_zero<<<SCAN_NBLK, 256, 0, stream>>>(cnt);
    k_pre<<<N_NODES * 32 / 256, 256, 0, stream>>>(x, xb, dst, cnt,
                                                  W1l, W1r, W2l, W2r, bpk1, bpk2);
    k_scan_part<<<SCAN_NBLK, 256, 0, stream>>>(cnt, rowptr, bsum);
    k_scan_add2<<<SCAN_NBLK, 256, 0, stream>>>(rowptr, bsum, cursor);
    {
        int chunks = (E_EDGES + 255) / 256;           // 3125
        k_fill_shard<<<chunks * NSHARD, 256, 0, stream>>>(src, dst, cursor, eidx);
    }

    // ---- fused gather + dense1 + dense2 ----
    k_fused<<<N_NODES / 16, 256, 0, stream>>>(rowptr, eidx, xb, bpk1, bpk2,
                                              b1, b2, zl, zr);

    // ---- layer-2 gather ----
    k_gather40<<<(N_NODES + 63) / 64, 320, 0, stream>>>(rowptr, eidx, zl, zr, outp);
}